// Round 2
// baseline (467.505 us; speedup 1.0000x reference)
//
#include <hip/hip_runtime.h>

#define BB 4
#define CC 256
#define NN 4096
#define II 128

typedef float f32x4 __attribute__((ext_vector_type(4)));
typedef __bf16 bf16x8 __attribute__((ext_vector_type(8)));

static __device__ __forceinline__ unsigned short f2bf(float f) {
    unsigned int u = __builtin_bit_cast(unsigned int, f);
    u += 0x7fffu + ((u >> 16) & 1u);
    return (unsigned short)(u >> 16);
}
static __device__ __forceinline__ float bf2f(unsigned short s) {
    return __builtin_bit_cast(float, (unsigned int)s << 16);
}

// ---------------- w_out f32 -> bf16 ----------------
__global__ void conv_wout_kernel(const float* __restrict__ w, unsigned short* __restrict__ o) {
    int i = blockIdx.x * 256 + threadIdx.x;   // grid covers CC*II
    o[i] = f2bf(w[i]);
}

// ---------------- projections: out[i][n] = sum_c w[i][c] x[b][c][n] + bias[i] ----------------
// f32 accumulate, split bf16 store (hi + residual lo) for Q/K; transposed hi-only for V.
// mode==0: out_hi/out_lo are [B][N][II] (n-major rows)   (Q, K)
// mode==1: out_hi is [B][II][N] (i-major rows), no lo    (V)
__global__ __launch_bounds__(256) void proj_kernel(
    const float* __restrict__ x, const float* __restrict__ w,
    const float* __restrict__ bias, unsigned short* __restrict__ out_hi,
    unsigned short* __restrict__ out_lo, int mode)
{
    __shared__ float xs[32][68];     // [c][n] chunk
    __shared__ float wsm[128][33];   // [i][c] chunk
    int tid = threadIdx.x;
    int b = blockIdx.y;
    int n0 = blockIdx.x * 64;
    int ti = tid & 15, tn = tid >> 4;   // i-group from low bits (coalesced stores)
    int i0 = ti * 8, nb = tn * 4;
    float acc[8][4];
    #pragma unroll
    for (int u = 0; u < 8; ++u)
        #pragma unroll
        for (int v = 0; v < 4; ++v) acc[u][v] = 0.0f;

    const float* xb = x + b * CC * NN;
    for (int c0 = 0; c0 < CC; c0 += 32) {
        #pragma unroll
        for (int r = 0; r < 8; ++r) {
            int idx = r * 256 + tid;
            int c = idx >> 6, n2 = idx & 63;
            xs[c][n2] = xb[(c0 + c) * NN + n0 + n2];
        }
        #pragma unroll
        for (int r = 0; r < 16; ++r) {
            int idx = r * 256 + tid;
            int ii = idx >> 5, c = idx & 31;
            wsm[ii][c] = w[ii * CC + c0 + c];
        }
        __syncthreads();
        #pragma unroll
        for (int c = 0; c < 32; ++c) {
            float4 xv = *(const float4*)&xs[c][nb];
            #pragma unroll
            for (int u = 0; u < 8; ++u) {
                float wv = wsm[i0 + u][c];
                acc[u][0] += wv * xv.x;
                acc[u][1] += wv * xv.y;
                acc[u][2] += wv * xv.z;
                acc[u][3] += wv * xv.w;
            }
        }
        __syncthreads();
    }
    #pragma unroll
    for (int u = 0; u < 8; ++u) {
        float bv = bias[i0 + u];
        #pragma unroll
        for (int v = 0; v < 4; ++v) acc[u][v] += bv;
    }
    if (mode == 0) {
        #pragma unroll
        for (int v = 0; v < 4; ++v) {
            union { unsigned short s[8]; uint4 q; } ph, pl;
            #pragma unroll
            for (int u = 0; u < 8; ++u) {
                unsigned short h = f2bf(acc[u][v]);
                ph.s[u] = h;
                pl.s[u] = f2bf(acc[u][v] - bf2f(h));
            }
            size_t off = (size_t)(b * NN + n0 + nb + v) * II + i0;
            *(uint4*)&out_hi[off] = ph.q;
            *(uint4*)&out_lo[off] = pl.q;
        }
    } else {
        #pragma unroll
        for (int u = 0; u < 8; ++u) {
            union { unsigned short s[4]; uint2 q; } pk;
            #pragma unroll
            for (int v = 0; v < 4; ++v) pk.s[v] = f2bf(acc[u][v]);
            *(uint2*)&out_hi[(b * II + i0 + u) * NN + n0 + nb] = pk.q;
        }
    }
}

// ---------------- flash attention + fused output conv + residual ----------------
// grid (NN/64, BB), 256 threads = 4 waves; wave w owns q-rows qt*64 + w*16 .. +15.
// Split-precision logits: S = qh*kh + ql*kh + qh*kl  (f32-accurate).
__global__ __launch_bounds__(256) void attn_kernel(
    const unsigned short* __restrict__ Qh,   // [B][N][II] bf16 hi
    const unsigned short* __restrict__ Ql,   // [B][N][II] bf16 lo
    const unsigned short* __restrict__ Kh,   // [B][N][II] bf16 hi
    const unsigned short* __restrict__ Kl,   // [B][N][II] bf16 lo
    const unsigned short* __restrict__ Vb,   // [B][II][N] bf16
    const unsigned short* __restrict__ Wo,   // [CC][II] bf16
    const float* __restrict__ b_out,
    const float* __restrict__ x,
    float* __restrict__ out)
{
    __shared__ unsigned short Ksh[64 * 128];   // 256B rows, XOR-swizzled
    __shared__ unsigned short Ksl[64 * 128];   // 256B rows, XOR-swizzled
    __shared__ unsigned short Vs[128 * 64];    // 128B rows, XOR-swizzled (V^T tile [i][m])
    __shared__ unsigned short Ps[4][16 * 64];  // per-wave P, 128B rows, swizzled

    int tid = threadIdx.x;
    int w = tid >> 6, l = tid & 63, g = l >> 4, cl = l & 15;
    int b = blockIdx.y, qt = blockIdx.x;
    int qr0 = qt * 64;

    // Q A-fragments straight from global (loop-invariant)
    bf16x8 qah[4], qal[4];
    {
        const unsigned short* qrow_h = Qh + (size_t)(b * NN + qr0 + w * 16 + cl) * II;
        const unsigned short* qrow_l = Ql + (size_t)(b * NN + qr0 + w * 16 + cl) * II;
        #pragma unroll
        for (int kc = 0; kc < 4; ++kc) {
            qah[kc] = *(const bf16x8*)(qrow_h + kc * 32 + g * 8);
            qal[kc] = *(const bf16x8*)(qrow_l + kc * 32 + g * 8);
        }
    }

    f32x4 zero4 = {0.f, 0.f, 0.f, 0.f};
    f32x4 yacc[8];
    #pragma unroll
    for (int it = 0; it < 8; ++it) yacc[it] = zero4;
    float mrun[4], lrun[4];
    #pragma unroll
    for (int r = 0; r < 4; ++r) { mrun[r] = -1e30f; lrun[r] = 0.f; }

    for (int m0 = 0; m0 < NN; m0 += 64) {
        // ---- stage K tiles (hi+lo) [64 m][128 i] and V^T tile [128 i][64 m] ----
        {
            const unsigned short* kbh = Kh + (size_t)(b * NN + m0) * II;
            const unsigned short* kbl = Kl + (size_t)(b * NN + m0) * II;
            #pragma unroll
            for (int r = 0; r < 4; ++r) {
                int idx = r * 256 + tid;
                int row = idx >> 4, ch = idx & 15;
                int dst = row * 256 + ((ch ^ (row & 7)) << 4);
                *(uint4*)((char*)Ksh + dst) = *(const uint4*)(kbh + row * II + ch * 8);
                *(uint4*)((char*)Ksl + dst) = *(const uint4*)(kbl + row * II + ch * 8);
            }
            const unsigned short* vb = Vb + (size_t)b * II * NN + m0;
            #pragma unroll
            for (int r = 0; r < 4; ++r) {
                int idx = r * 256 + tid;
                int row = idx >> 3, ch = idx & 7;
                uint4 v = *(const uint4*)(vb + row * NN + ch * 8);
                *(uint4*)((char*)Vs + row * 128 + ((ch ^ (row & 7)) << 4)) = v;
            }
        }
        __syncthreads();

        // ---- S = Q K^T (split precision) ----
        f32x4 sacc[4];
        #pragma unroll
        for (int mt = 0; mt < 4; ++mt) sacc[mt] = zero4;
        #pragma unroll
        for (int mt = 0; mt < 4; ++mt) {
            int row = mt * 16 + cl;
            #pragma unroll
            for (int kc = 0; kc < 4; ++kc) {
                int off = row * 256 + (((kc * 4 + g) ^ (row & 7)) << 4);
                bf16x8 kh = *(const bf16x8*)((const char*)Ksh + off);
                bf16x8 kl = *(const bf16x8*)((const char*)Ksl + off);
                sacc[mt] = __builtin_amdgcn_mfma_f32_16x16x32_bf16(qah[kc], kh, sacc[mt], 0, 0, 0);
                sacc[mt] = __builtin_amdgcn_mfma_f32_16x16x32_bf16(qal[kc], kh, sacc[mt], 0, 0, 0);
                sacc[mt] = __builtin_amdgcn_mfma_f32_16x16x32_bf16(qah[kc], kl, sacc[mt], 0, 0, 0);
            }
        }

        // ---- online softmax (per 16-lane group; reg r <-> q-row 4g+r) ----
        float mnew[4], corr[4], psum[4];
        #pragma unroll
        for (int r = 0; r < 4; ++r) {
            float v = fmaxf(fmaxf(sacc[0][r], sacc[1][r]), fmaxf(sacc[2][r], sacc[3][r]));
            v = fmaxf(v, __shfl_xor(v, 1));
            v = fmaxf(v, __shfl_xor(v, 2));
            v = fmaxf(v, __shfl_xor(v, 4));
            v = fmaxf(v, __shfl_xor(v, 8));
            mnew[r] = fmaxf(mrun[r], v);
            corr[r] = __expf(mrun[r] - mnew[r]);
            mrun[r] = mnew[r];
            psum[r] = 0.f;
        }
        unsigned short* pw = Ps[w];
        #pragma unroll
        for (int mt = 0; mt < 4; ++mt) {
            #pragma unroll
            for (int r = 0; r < 4; ++r) {
                float p = __expf(sacc[mt][r] - mnew[r]);
                unsigned short pu = f2bf(p);
                psum[r] += bf2f(pu);   // denominator from the rounded P (unbiased PV)
                int prow = 4 * g + r, pcol = mt * 16 + cl;
                *(unsigned short*)((char*)pw + prow * 128 + ((pcol * 2) ^ ((prow & 7) << 4))) = pu;
            }
        }
        #pragma unroll
        for (int r = 0; r < 4; ++r) {
            float s = psum[r];
            s += __shfl_xor(s, 1);
            s += __shfl_xor(s, 2);
            s += __shfl_xor(s, 4);
            s += __shfl_xor(s, 8);
            lrun[r] = lrun[r] * corr[r] + s;
        }
        #pragma unroll
        for (int it = 0; it < 8; ++it)
            #pragma unroll
            for (int r = 0; r < 4; ++r) yacc[it][r] *= corr[r];

        // ---- Y += P V ----
        bf16x8 pa[2];
        #pragma unroll
        for (int k2 = 0; k2 < 2; ++k2)
            pa[k2] = *(const bf16x8*)((const char*)pw + cl * 128 + (((k2 * 4 + g) ^ (cl & 7)) << 4));
        #pragma unroll
        for (int it = 0; it < 8; ++it) {
            #pragma unroll
            for (int k2 = 0; k2 < 2; ++k2) {
                int row = it * 16 + cl;
                bf16x8 vf = *(const bf16x8*)((const char*)Vs + row * 128 + (((k2 * 4 + g) ^ (row & 7)) << 4));
                yacc[it] = __builtin_amdgcn_mfma_f32_16x16x32_bf16(pa[k2], vf, yacc[it], 0, 0, 0);
            }
        }
        __syncthreads();
    }

    // ---- normalize and park Y (bf16) in per-wave LDS region (reuse Ksh) ----
    float rl[4];
    #pragma unroll
    for (int r = 0; r < 4; ++r) rl[r] = 1.0f / lrun[r];
    unsigned short* ys = Ksh + w * (16 * 128);
    #pragma unroll
    for (int it = 0; it < 8; ++it) {
        #pragma unroll
        for (int r = 0; r < 4; ++r) {
            float yv = yacc[it][r] * rl[r];
            int row = 4 * g + r;          // n-local
            int col = it * 16 + cl;       // i
            *(unsigned short*)((char*)ys + row * 256 + ((col * 2) ^ ((row & 7) << 4))) = f2bf(yv);
        }
    }
    // same-wave write->read only; no cross-wave sharing, no barrier needed

    // ---- out[c][n] = sum_i Wo[c][i] Y[n][i] + b_out[c] + x[b][c][n] ----
    bf16x8 yf[4];
    #pragma unroll
    for (int kc = 0; kc < 4; ++kc)
        yf[kc] = *(const bf16x8*)((const char*)ys + cl * 256 + (((kc * 4 + g) ^ (cl & 7)) << 4));
    int n = qr0 + w * 16 + cl;
    for (int ct = 0; ct < 16; ++ct) {
        f32x4 oa = zero4;
        #pragma unroll
        for (int kc = 0; kc < 4; ++kc) {
            bf16x8 wf = *(const bf16x8*)(Wo + (ct * 16 + cl) * II + kc * 32 + g * 8);
            oa = __builtin_amdgcn_mfma_f32_16x16x32_bf16(wf, yf[kc], oa, 0, 0, 0);
        }
        #pragma unroll
        for (int r = 0; r < 4; ++r) {
            int c = ct * 16 + 4 * g + r;
            size_t off = (size_t)(b * CC + c) * NN + n;
            out[off] = oa[r] + b_out[c] + x[off];
        }
    }
}

extern "C" void kernel_launch(void* const* d_in, const int* in_sizes, int n_in,
                              void* d_out, int out_size, void* d_ws, size_t ws_size,
                              hipStream_t stream) {
    const float* x     = (const float*)d_in[0];
    const float* w_g   = (const float*)d_in[1];
    const float* b_g   = (const float*)d_in[2];
    const float* w_th  = (const float*)d_in[3];
    const float* b_th  = (const float*)d_in[4];
    const float* w_ph  = (const float*)d_in[5];
    const float* b_ph  = (const float*)d_in[6];
    const float* w_out = (const float*)d_in[7];
    const float* b_o   = (const float*)d_in[8];
    float* out = (float*)d_out;

    const size_t SZ = (size_t)BB * NN * II;
    unsigned short* Qh = (unsigned short*)d_ws;
    unsigned short* Ql = Qh + SZ;
    unsigned short* Kh = Ql + SZ;
    unsigned short* Kl = Kh + SZ;
    unsigned short* Vb = Kl + SZ;
    unsigned short* Wo = Vb + SZ;

    conv_wout_kernel<<<dim3((CC * II) / 256), dim3(256), 0, stream>>>(w_out, Wo);
    dim3 g1(NN / 64, BB), t1(256);
    proj_kernel<<<g1, t1, 0, stream>>>(x, w_th, b_th, Qh, Ql, 0);  // theta -> Q hi/lo
    proj_kernel<<<g1, t1, 0, stream>>>(x, w_ph, b_ph, Kh, Kl, 0);  // phi   -> K hi/lo
    proj_kernel<<<g1, t1, 0, stream>>>(x, w_g,  b_g,  Vb, nullptr, 1);  // g -> V^T
    attn_kernel<<<dim3(NN / 64, BB), dim3(256), 0, stream>>>(Qh, Ql, Kh, Kl, Vb, Wo, b_o, x, out);
}

// Round 3
// 336.266 us; speedup vs baseline: 1.3903x; 1.3903x over previous
//
#include <hip/hip_runtime.h>

#define BB 4
#define CC 256
#define NN 4096
#define II 128
#define NSPLIT 2
#define KVH (NN / NSPLIT)   // 2048 KV rows per split
#define NT (KVH / 64)       // 32 tiles per split

typedef float f32x4 __attribute__((ext_vector_type(4)));
typedef __bf16 bf16x8 __attribute__((ext_vector_type(8)));

static __device__ __forceinline__ unsigned short f2bf(float f) {
    unsigned int u = __builtin_bit_cast(unsigned int, f);
    u += 0x7fffu + ((u >> 16) & 1u);
    return (unsigned short)(u >> 16);
}
static __device__ __forceinline__ float bf2f(unsigned short s) {
    return __builtin_bit_cast(float, (unsigned int)s << 16);
}

// ---------------- w_out f32 -> bf16 ----------------
__global__ void conv_wout_kernel(const float* __restrict__ w, unsigned short* __restrict__ o) {
    int i = blockIdx.x * 256 + threadIdx.x;   // grid covers CC*II
    o[i] = f2bf(w[i]);
}

// ---------------- fused projections: theta->Q(hi/lo), phi->K(hi/lo), g->V^T ----------------
__global__ __launch_bounds__(256) void proj3_kernel(
    const float* __restrict__ x,
    const float* __restrict__ w_th, const float* __restrict__ b_th,
    const float* __restrict__ w_ph, const float* __restrict__ b_ph,
    const float* __restrict__ w_g,  const float* __restrict__ b_g,
    unsigned short* __restrict__ Qh, unsigned short* __restrict__ Ql,
    unsigned short* __restrict__ Kh, unsigned short* __restrict__ Kl,
    unsigned short* __restrict__ Vt)
{
    __shared__ float xs[32][68];        // [c][n] chunk
    __shared__ float wsm[3][128][33];   // [mat][i][c] chunk
    int tid = threadIdx.x;
    int b = blockIdx.y;
    int n0 = blockIdx.x * 64;
    int ti = tid & 15, tn = tid >> 4;
    int i0 = ti * 8, nb = tn * 4;
    float acc[3][8][4];
    #pragma unroll
    for (int m = 0; m < 3; ++m)
        #pragma unroll
        for (int u = 0; u < 8; ++u)
            #pragma unroll
            for (int v = 0; v < 4; ++v) acc[m][u][v] = 0.0f;

    const float* wp[3] = {w_th, w_ph, w_g};
    const float* xb = x + b * CC * NN;
    for (int c0 = 0; c0 < CC; c0 += 32) {
        #pragma unroll
        for (int r = 0; r < 8; ++r) {
            int idx = r * 256 + tid;
            int c = idx >> 6, n2 = idx & 63;
            xs[c][n2] = xb[(c0 + c) * NN + n0 + n2];
        }
        #pragma unroll
        for (int m = 0; m < 3; ++m)
            #pragma unroll
            for (int r = 0; r < 16; ++r) {
                int idx = r * 256 + tid;
                int ii = idx >> 5, c = idx & 31;
                wsm[m][ii][c] = wp[m][ii * CC + c0 + c];
            }
        __syncthreads();
        #pragma unroll 8
        for (int c = 0; c < 32; ++c) {
            float4 xv = *(const float4*)&xs[c][nb];
            #pragma unroll
            for (int m = 0; m < 3; ++m)
                #pragma unroll
                for (int u = 0; u < 8; ++u) {
                    float wv = wsm[m][i0 + u][c];
                    acc[m][u][0] += wv * xv.x;
                    acc[m][u][1] += wv * xv.y;
                    acc[m][u][2] += wv * xv.z;
                    acc[m][u][3] += wv * xv.w;
                }
        }
        __syncthreads();
    }
    const float* bp[3] = {b_th, b_ph, b_g};
    #pragma unroll
    for (int m = 0; m < 3; ++m) {
        #pragma unroll
        for (int u = 0; u < 8; ++u) {
            float bv = bp[m][i0 + u];
            #pragma unroll
            for (int v = 0; v < 4; ++v) acc[m][u][v] += bv;
        }
    }
    // Q (m=0) and K (m=1): hi/lo, [B][N][II]
    #pragma unroll
    for (int m = 0; m < 2; ++m) {
        unsigned short* oh = (m == 0) ? Qh : Kh;
        unsigned short* ol = (m == 0) ? Ql : Kl;
        #pragma unroll
        for (int v = 0; v < 4; ++v) {
            union { unsigned short s[8]; uint4 q; } ph, pl;
            #pragma unroll
            for (int u = 0; u < 8; ++u) {
                unsigned short h = f2bf(acc[m][u][v]);
                ph.s[u] = h;
                pl.s[u] = f2bf(acc[m][u][v] - bf2f(h));
            }
            size_t off = (size_t)(b * NN + n0 + nb + v) * II + i0;
            *(uint4*)&oh[off] = ph.q;
            *(uint4*)&ol[off] = pl.q;
        }
    }
    // V (m=2): transposed [B][II][N]
    #pragma unroll
    for (int u = 0; u < 8; ++u) {
        union { unsigned short s[4]; uint2 q; } pk;
        #pragma unroll
        for (int v = 0; v < 4; ++v) pk.s[v] = f2bf(acc[2][u][v]);
        *(uint2*)&Vt[(size_t)(b * II + i0 + u) * NN + n0 + nb] = pk.q;
    }
}

// ---------------- flash attention (split-K over KV), partial outputs ----------------
// 1-D grid 512; id&7 = XCD under round-robin: b=(id&7)>>1, split=id&1, qt=id>>3.
// Each XCD's L2 then caches one (batch, KV-half): ~1.5 MB resident.
__global__ __launch_bounds__(256, 2) void attn_kernel(
    const unsigned short* __restrict__ Qh, const unsigned short* __restrict__ Ql,
    const unsigned short* __restrict__ Kh, const unsigned short* __restrict__ Kl,
    const unsigned short* __restrict__ Vb,
    unsigned short* __restrict__ Yp,       // [NSPLIT][B][N][II] bf16, normalized partial
    float2* __restrict__ ML)               // [NSPLIT][B][N] {m,l}
{
    __shared__ unsigned short Ksh[64 * 128];
    __shared__ unsigned short Ksl[64 * 128];
    __shared__ unsigned short Vs[128 * 64];
    __shared__ unsigned short Ps[4][16 * 64];

    int tid = threadIdx.x;
    int w = tid >> 6, l = tid & 63, g = l >> 4, cl = l & 15;
    int id = blockIdx.x;
    int xcd = id & 7;
    int b = xcd >> 1, sp = xcd & 1, qt = id >> 3;
    int qr0 = qt * 64;
    int m_base = sp * KVH;

    // Q A-fragments (loop-invariant)
    bf16x8 qah[4], qal[4];
    {
        const unsigned short* qrow_h = Qh + (size_t)(b * NN + qr0 + w * 16 + cl) * II;
        const unsigned short* qrow_l = Ql + (size_t)(b * NN + qr0 + w * 16 + cl) * II;
        #pragma unroll
        for (int kc = 0; kc < 4; ++kc) {
            qah[kc] = *(const bf16x8*)(qrow_h + kc * 32 + g * 8);
            qal[kc] = *(const bf16x8*)(qrow_l + kc * 32 + g * 8);
        }
    }

    f32x4 zero4 = {0.f, 0.f, 0.f, 0.f};
    f32x4 yacc[8];
    #pragma unroll
    for (int it = 0; it < 8; ++it) yacc[it] = zero4;
    float mrun[4], lrun[4];
    #pragma unroll
    for (int r = 0; r < 4; ++r) { mrun[r] = -1e30f; lrun[r] = 0.f; }

    const unsigned short* kbh = Kh + (size_t)(b * NN + m_base) * II;
    const unsigned short* kbl = Kl + (size_t)(b * NN + m_base) * II;
    const unsigned short* vb  = Vb + (size_t)b * II * NN + m_base;
    int krow = tid >> 4, kch = tid & 15;   // K: 16 rows/round, 16 chunks of 8
    int vrow = tid >> 3, vch = tid & 7;    // V: 32 rows/round, 8 chunks of 8

    uint4 rkh[4], rkl[4], rv[4];
    // prefetch tile 0
    #pragma unroll
    for (int r = 0; r < 4; ++r) {
        rkh[r] = *(const uint4*)(kbh + (size_t)(r * 16 + krow) * II + kch * 8);
        rkl[r] = *(const uint4*)(kbl + (size_t)(r * 16 + krow) * II + kch * 8);
        rv[r]  = *(const uint4*)(vb + (size_t)(r * 32 + vrow) * NN + vch * 8);
    }

    for (int t = 0; t < NT; ++t) {
        __syncthreads();   // previous tile's compute done; LDS free
        // publish tile t from regs
        #pragma unroll
        for (int r = 0; r < 4; ++r) {
            int kdst = (r * 16 + krow) * 256 + ((kch ^ (krow & 7)) << 4);
            *(uint4*)((char*)Ksh + kdst) = rkh[r];
            *(uint4*)((char*)Ksl + kdst) = rkl[r];
            int vdst = (r * 32 + vrow) * 128 + ((vch ^ (vrow & 7)) << 4);
            *(uint4*)((char*)Vs + vdst) = rv[r];
        }
        __syncthreads();
        // issue next tile's loads (overlap with compute below)
        if (t + 1 < NT) {
            size_t toff = (size_t)(t + 1) * 64;
            #pragma unroll
            for (int r = 0; r < 4; ++r) {
                rkh[r] = *(const uint4*)(kbh + (toff + r * 16 + krow) * II + kch * 8);
                rkl[r] = *(const uint4*)(kbl + (toff + r * 16 + krow) * II + kch * 8);
                rv[r]  = *(const uint4*)(vb + (size_t)(r * 32 + vrow) * NN + toff + vch * 8);
            }
        }

        // ---- S = Q K^T (split precision) ----
        f32x4 sacc[4];
        #pragma unroll
        for (int mt = 0; mt < 4; ++mt) sacc[mt] = zero4;
        #pragma unroll
        for (int mt = 0; mt < 4; ++mt) {
            int row = mt * 16 + cl;
            #pragma unroll
            for (int kc = 0; kc < 4; ++kc) {
                int off = row * 256 + (((kc * 4 + g) ^ (row & 7)) << 4);
                bf16x8 kh = *(const bf16x8*)((const char*)Ksh + off);
                bf16x8 kl = *(const bf16x8*)((const char*)Ksl + off);
                sacc[mt] = __builtin_amdgcn_mfma_f32_16x16x32_bf16(qah[kc], kh, sacc[mt], 0, 0, 0);
                sacc[mt] = __builtin_amdgcn_mfma_f32_16x16x32_bf16(qal[kc], kh, sacc[mt], 0, 0, 0);
                sacc[mt] = __builtin_amdgcn_mfma_f32_16x16x32_bf16(qah[kc], kl, sacc[mt], 0, 0, 0);
            }
        }

        // ---- online softmax ----
        float mnew[4], corr[4], psum[4];
        #pragma unroll
        for (int r = 0; r < 4; ++r) {
            float v = fmaxf(fmaxf(sacc[0][r], sacc[1][r]), fmaxf(sacc[2][r], sacc[3][r]));
            v = fmaxf(v, __shfl_xor(v, 1));
            v = fmaxf(v, __shfl_xor(v, 2));
            v = fmaxf(v, __shfl_xor(v, 4));
            v = fmaxf(v, __shfl_xor(v, 8));
            mnew[r] = fmaxf(mrun[r], v);
            corr[r] = __expf(mrun[r] - mnew[r]);
            mrun[r] = mnew[r];
            psum[r] = 0.f;
        }
        unsigned short* pw = Ps[w];
        #pragma unroll
        for (int mt = 0; mt < 4; ++mt) {
            #pragma unroll
            for (int r = 0; r < 4; ++r) {
                float p = __expf(sacc[mt][r] - mnew[r]);
                unsigned short pu = f2bf(p);
                psum[r] += bf2f(pu);
                int prow = 4 * g + r, pcol = mt * 16 + cl;
                *(unsigned short*)((char*)pw + prow * 128 + ((pcol * 2) ^ ((prow & 7) << 4))) = pu;
            }
        }
        #pragma unroll
        for (int r = 0; r < 4; ++r) {
            float s = psum[r];
            s += __shfl_xor(s, 1);
            s += __shfl_xor(s, 2);
            s += __shfl_xor(s, 4);
            s += __shfl_xor(s, 8);
            lrun[r] = lrun[r] * corr[r] + s;
        }
        #pragma unroll
        for (int it = 0; it < 8; ++it)
            #pragma unroll
            for (int r = 0; r < 4; ++r) yacc[it][r] *= corr[r];

        // ---- Y += P V ----
        bf16x8 pa[2];
        #pragma unroll
        for (int k2 = 0; k2 < 2; ++k2)
            pa[k2] = *(const bf16x8*)((const char*)pw + cl * 128 + (((k2 * 4 + g) ^ (cl & 7)) << 4));
        #pragma unroll
        for (int it = 0; it < 8; ++it) {
            #pragma unroll
            for (int k2 = 0; k2 < 2; ++k2) {
                int row = it * 16 + cl;
                bf16x8 vf = *(const bf16x8*)((const char*)Vs + row * 128 + (((k2 * 4 + g) ^ (row & 7)) << 4));
                yacc[it] = __builtin_amdgcn_mfma_f32_16x16x32_bf16(pa[k2], vf, yacc[it], 0, 0, 0);
            }
        }
    }

    // ---- store normalized partial Y (bf16) + (m,l) ----
    float rl[4];
    #pragma unroll
    for (int r = 0; r < 4; ++r) rl[r] = 1.0f / lrun[r];
    size_t rowbase = (size_t)((sp * BB + b) * NN + qr0 + w * 16);
    #pragma unroll
    for (int it = 0; it < 8; ++it)
        #pragma unroll
        for (int r = 0; r < 4; ++r)
            Yp[(rowbase + 4 * g + r) * II + it * 16 + cl] = f2bf(yacc[it][r] * rl[r]);
    if (cl == 0) {
        #pragma unroll
        for (int r = 0; r < 4; ++r) {
            float2 v; v.x = mrun[r]; v.y = lrun[r];
            ML[rowbase + 4 * g + r] = v;
        }
    }
}

// ---------------- combine partials + output conv + bias + residual ----------------
__global__ __launch_bounds__(256) void combine_kernel(
    const unsigned short* __restrict__ Yp, const float2* __restrict__ ML,
    const unsigned short* __restrict__ Wo, const float* __restrict__ b_out,
    const float* __restrict__ x, float* __restrict__ out)
{
    __shared__ unsigned short Ys[4][16 * 128];   // per-wave park, swizzled 256B rows

    int tid = threadIdx.x;
    int w = tid >> 6, l = tid & 63, g = l >> 4, cl = l & 15;
    int qt = blockIdx.x, b = blockIdx.y;
    int qr0 = qt * 64;
    int n = qr0 + w * 16 + cl;

    size_t r0 = (size_t)((0 * BB + b) * NN + n);
    size_t r1 = (size_t)((1 * BB + b) * NN + n);
    float2 ml0 = ML[r0], ml1 = ML[r1];
    float M = fmaxf(ml0.x, ml1.x);
    float w0 = __expf(ml0.x - M) * ml0.y;
    float w1 = __expf(ml1.x - M) * ml1.y;
    float rd = 1.0f / (w0 + w1);
    w0 *= rd; w1 *= rd;

    unsigned short* ys = Ys[w];
    #pragma unroll
    for (int j = 0; j < 4; ++j) {
        union { unsigned short s[8]; uint4 q; } a, c, o;
        a.q = *(const uint4*)(Yp + r0 * II + g * 32 + j * 8);
        c.q = *(const uint4*)(Yp + r1 * II + g * 32 + j * 8);
        #pragma unroll
        for (int e = 0; e < 8; ++e)
            o.s[e] = f2bf(w0 * bf2f(a.s[e]) + w1 * bf2f(c.s[e]));
        *(uint4*)((char*)ys + cl * 256 + (((g * 4 + j) ^ (cl & 7)) << 4)) = o.q;
    }
    // same-wave write->read; no barrier needed

    f32x4 zero4 = {0.f, 0.f, 0.f, 0.f};
    bf16x8 yf[4];
    #pragma unroll
    for (int kc = 0; kc < 4; ++kc)
        yf[kc] = *(const bf16x8*)((const char*)ys + cl * 256 + (((kc * 4 + g) ^ (cl & 7)) << 4));
    for (int ct = 0; ct < 16; ++ct) {
        f32x4 oa = zero4;
        #pragma unroll
        for (int kc = 0; kc < 4; ++kc) {
            bf16x8 wf = *(const bf16x8*)(Wo + (ct * 16 + cl) * II + kc * 32 + g * 8);
            oa = __builtin_amdgcn_mfma_f32_16x16x32_bf16(wf, yf[kc], oa, 0, 0, 0);
        }
        #pragma unroll
        for (int r = 0; r < 4; ++r) {
            int c = ct * 16 + 4 * g + r;
            size_t off = (size_t)(b * CC + c) * NN + n;
            out[off] = oa[r] + b_out[c] + x[off];
        }
    }
}

extern "C" void kernel_launch(void* const* d_in, const int* in_sizes, int n_in,
                              void* d_out, int out_size, void* d_ws, size_t ws_size,
                              hipStream_t stream) {
    const float* x     = (const float*)d_in[0];
    const float* w_g   = (const float*)d_in[1];
    const float* b_g   = (const float*)d_in[2];
    const float* w_th  = (const float*)d_in[3];
    const float* b_th  = (const float*)d_in[4];
    const float* w_ph  = (const float*)d_in[5];
    const float* b_ph  = (const float*)d_in[6];
    const float* w_out = (const float*)d_in[7];
    const float* b_o   = (const float*)d_in[8];
    float* out = (float*)d_out;

    const size_t SZ = (size_t)BB * NN * II;
    unsigned short* Qh = (unsigned short*)d_ws;
    unsigned short* Ql = Qh + SZ;
    unsigned short* Kh = Ql + SZ;
    unsigned short* Kl = Kh + SZ;
    unsigned short* Vb = Kl + SZ;
    unsigned short* Wo = Vb + SZ;
    unsigned short* Yp = Wo + (size_t)CC * II;                 // NSPLIT * SZ bf16
    float2*         ML = (float2*)(Yp + (size_t)NSPLIT * SZ);  // NSPLIT*B*N float2

    conv_wout_kernel<<<dim3((CC * II) / 256), dim3(256), 0, stream>>>(w_out, Wo);
    proj3_kernel<<<dim3(NN / 64, BB), dim3(256), 0, stream>>>(
        x, w_th, b_th, w_ph, b_ph, w_g, b_g, Qh, Ql, Kh, Kl, Vb);
    attn_kernel<<<dim3(NSPLIT * BB * (NN / 64)), dim3(256), 0, stream>>>(
        Qh, Ql, Kh, Kl, Vb, Yp, ML);
    combine_kernel<<<dim3(NN / 64, BB), dim3(256), 0, stream>>>(Yp, ML, Wo, b_o, x, out);
}

// Round 4
// 266.779 us; speedup vs baseline: 1.7524x; 1.2605x over previous
//
#include <hip/hip_runtime.h>

#define BB 4
#define CC 256
#define NN 4096
#define II 128
#define NSPLIT 4
#define KVH (NN / NSPLIT)   // 1024 KV rows per split
#define NT (KVH / 64)       // 16 tiles per split

typedef float f32x4 __attribute__((ext_vector_type(4)));
typedef _Float16 f16x8 __attribute__((ext_vector_type(8)));

static __device__ __forceinline__ unsigned short f2h(float f) {
    _Float16 h = (_Float16)f;
    return __builtin_bit_cast(unsigned short, h);
}
static __device__ __forceinline__ float h2f(unsigned short s) {
    return (float)__builtin_bit_cast(_Float16, s);
}

// ---------------- w_out f32 -> fp16 ----------------
__global__ void conv_wout_kernel(const float* __restrict__ w, unsigned short* __restrict__ o) {
    int i = blockIdx.x * 256 + threadIdx.x;   // grid covers CC*II
    o[i] = f2h(w[i]);
}

// ---------------- fused projections: theta->Q, phi->K, g->V^T (all fp16) ----------------
__global__ __launch_bounds__(256) void proj3_kernel(
    const float* __restrict__ x,
    const float* __restrict__ w_th, const float* __restrict__ b_th,
    const float* __restrict__ w_ph, const float* __restrict__ b_ph,
    const float* __restrict__ w_g,  const float* __restrict__ b_g,
    unsigned short* __restrict__ Qb, unsigned short* __restrict__ Kb,
    unsigned short* __restrict__ Vt)
{
    __shared__ float xs[32][68];        // [c][n] chunk
    __shared__ float wsm[3][128][33];   // [mat][i][c] chunk
    int tid = threadIdx.x;
    int b = blockIdx.y;
    int n0 = blockIdx.x * 64;
    int ti = tid & 15, tn = tid >> 4;
    int i0 = ti * 8, nb = tn * 4;
    float acc[3][8][4];
    #pragma unroll
    for (int m = 0; m < 3; ++m)
        #pragma unroll
        for (int u = 0; u < 8; ++u)
            #pragma unroll
            for (int v = 0; v < 4; ++v) acc[m][u][v] = 0.0f;

    const float* wp[3] = {w_th, w_ph, w_g};
    const float* xb = x + b * CC * NN;
    for (int c0 = 0; c0 < CC; c0 += 32) {
        #pragma unroll
        for (int r = 0; r < 8; ++r) {
            int idx = r * 256 + tid;
            int c = idx >> 6, n2 = idx & 63;
            xs[c][n2] = xb[(c0 + c) * NN + n0 + n2];
        }
        #pragma unroll
        for (int m = 0; m < 3; ++m)
            #pragma unroll
            for (int r = 0; r < 16; ++r) {
                int idx = r * 256 + tid;
                int ii = idx >> 5, c = idx & 31;
                wsm[m][ii][c] = wp[m][ii * CC + c0 + c];
            }
        __syncthreads();
        #pragma unroll 8
        for (int c = 0; c < 32; ++c) {
            float4 xv = *(const float4*)&xs[c][nb];
            #pragma unroll
            for (int m = 0; m < 3; ++m)
                #pragma unroll
                for (int u = 0; u < 8; ++u) {
                    float wv = wsm[m][i0 + u][c];
                    acc[m][u][0] += wv * xv.x;
                    acc[m][u][1] += wv * xv.y;
                    acc[m][u][2] += wv * xv.z;
                    acc[m][u][3] += wv * xv.w;
                }
        }
        __syncthreads();
    }
    const float* bp[3] = {b_th, b_ph, b_g};
    #pragma unroll
    for (int m = 0; m < 3; ++m) {
        #pragma unroll
        for (int u = 0; u < 8; ++u) {
            float bv = bp[m][i0 + u];
            #pragma unroll
            for (int v = 0; v < 4; ++v) acc[m][u][v] += bv;
        }
    }
    // Q (m=0), K (m=1): [B][N][II] fp16
    #pragma unroll
    for (int m = 0; m < 2; ++m) {
        unsigned short* oh = (m == 0) ? Qb : Kb;
        #pragma unroll
        for (int v = 0; v < 4; ++v) {
            union { unsigned short s[8]; uint4 q; } ph;
            #pragma unroll
            for (int u = 0; u < 8; ++u) ph.s[u] = f2h(acc[m][u][v]);
            *(uint4*)&oh[(size_t)(b * NN + n0 + nb + v) * II + i0] = ph.q;
        }
    }
    // V (m=2): transposed [B][II][N] fp16
    #pragma unroll
    for (int u = 0; u < 8; ++u) {
        union { unsigned short s[4]; uint2 q; } pk;
        #pragma unroll
        for (int v = 0; v < 4; ++v) pk.s[v] = f2h(acc[2][u][v]);
        *(uint2*)&Vt[(size_t)(b * II + i0 + u) * NN + n0 + nb] = pk.q;
    }
}

// ---------------- flash attention (split-K over KV), partial outputs ----------------
// grid 1024: xcd = id&7 serves one batch b = xcd>>1 and two KV-quarters.
// comb = xcd*2 + ((id>>3)&1): b = comb>>2, sp = comb&3; qt = id>>4.
__global__ __launch_bounds__(256, 4) void attn_kernel(
    const unsigned short* __restrict__ Qb,   // [B][N][II] fp16
    const unsigned short* __restrict__ Kb,   // [B][N][II] fp16
    const unsigned short* __restrict__ Vb,   // [B][II][N] fp16
    unsigned short* __restrict__ Yp,         // [NSPLIT][B][N][II] fp16, normalized partial
    float2* __restrict__ ML)                 // [NSPLIT][B][N] {m,l}
{
    __shared__ unsigned short Ks[64 * 128];   // 256B rows, XOR-swizzled (16 KB)
    __shared__ unsigned short Vs[128 * 64];   // 128B rows, XOR-swizzled (16 KB)
    __shared__ unsigned short Ps[4][16 * 64]; // per-wave P (8 KB)

    int tid = threadIdx.x;
    int w = tid >> 6, l = tid & 63, g = l >> 4, cl = l & 15;
    int id = blockIdx.x;
    int comb = (id & 7) * 2 + ((id >> 3) & 1);
    int b = comb >> 2, sp = comb & 3, qt = id >> 4;
    int qr0 = qt * 64;
    int m_base = sp * KVH;

    // Q A-fragments (loop-invariant)
    f16x8 qa[4];
    {
        const unsigned short* qrow = Qb + (size_t)(b * NN + qr0 + w * 16 + cl) * II;
        #pragma unroll
        for (int kc = 0; kc < 4; ++kc)
            qa[kc] = *(const f16x8*)(qrow + kc * 32 + g * 8);
    }

    f32x4 zero4 = {0.f, 0.f, 0.f, 0.f};
    f32x4 yacc[8];
    #pragma unroll
    for (int it = 0; it < 8; ++it) yacc[it] = zero4;
    float mrun[4], lrun[4];
    #pragma unroll
    for (int r = 0; r < 4; ++r) { mrun[r] = -1e30f; lrun[r] = 0.f; }

    const unsigned short* kb = Kb + (size_t)(b * NN + m_base) * II;
    const unsigned short* vb = Vb + (size_t)b * II * NN + m_base;
    int krow = tid >> 4, kch = tid & 15;   // K: rows 16/round, 16 chunks of 8
    int vrow = tid >> 3, vch = tid & 7;    // V: rows 32/round, 8 chunks of 8
    int kswz = (kch ^ (krow & 7)) << 4;
    int vswz = (vch ^ (vrow & 7)) << 4;

    // named prefetch registers (NO arrays -> no PromoteAlloca to LDS)
    uint4 k0, k1, k2, k3, v0, v1, v2, v3;
    {
        k0 = *(const uint4*)(kb + (size_t)(krow) * II + kch * 8);
        k1 = *(const uint4*)(kb + (size_t)(16 + krow) * II + kch * 8);
        k2 = *(const uint4*)(kb + (size_t)(32 + krow) * II + kch * 8);
        k3 = *(const uint4*)(kb + (size_t)(48 + krow) * II + kch * 8);
        v0 = *(const uint4*)(vb + (size_t)(vrow) * NN + vch * 8);
        v1 = *(const uint4*)(vb + (size_t)(32 + vrow) * NN + vch * 8);
        v2 = *(const uint4*)(vb + (size_t)(64 + vrow) * NN + vch * 8);
        v3 = *(const uint4*)(vb + (size_t)(96 + vrow) * NN + vch * 8);
    }

    for (int t = 0; t < NT; ++t) {
        __syncthreads();   // previous tile's compute done; LDS free
        // publish tile t from regs
        *(uint4*)((char*)Ks + (krow) * 256 + kswz) = k0;
        *(uint4*)((char*)Ks + (16 + krow) * 256 + kswz) = k1;
        *(uint4*)((char*)Ks + (32 + krow) * 256 + kswz) = k2;
        *(uint4*)((char*)Ks + (48 + krow) * 256 + kswz) = k3;
        *(uint4*)((char*)Vs + (vrow) * 128 + vswz) = v0;
        *(uint4*)((char*)Vs + (32 + vrow) * 128 + vswz) = v1;
        *(uint4*)((char*)Vs + (64 + vrow) * 128 + vswz) = v2;
        *(uint4*)((char*)Vs + (96 + vrow) * 128 + vswz) = v3;
        __syncthreads();
        // issue next tile's loads (latency hides under compute below)
        if (t + 1 < NT) {
            const unsigned short* kp = kb + (size_t)(t + 1) * 64 * II;
            const unsigned short* vp = vb + (size_t)(t + 1) * 64;
            k0 = *(const uint4*)(kp + (size_t)(krow) * II + kch * 8);
            k1 = *(const uint4*)(kp + (size_t)(16 + krow) * II + kch * 8);
            k2 = *(const uint4*)(kp + (size_t)(32 + krow) * II + kch * 8);
            k3 = *(const uint4*)(kp + (size_t)(48 + krow) * II + kch * 8);
            v0 = *(const uint4*)(vp + (size_t)(vrow) * NN + vch * 8);
            v1 = *(const uint4*)(vp + (size_t)(32 + vrow) * NN + vch * 8);
            v2 = *(const uint4*)(vp + (size_t)(64 + vrow) * NN + vch * 8);
            v3 = *(const uint4*)(vp + (size_t)(96 + vrow) * NN + vch * 8);
        }

        // ---- S = Q K^T (fp16, single MFMA per fragment) ----
        f32x4 sacc[4];
        #pragma unroll
        for (int mt = 0; mt < 4; ++mt) sacc[mt] = zero4;
        __builtin_amdgcn_s_setprio(1);
        #pragma unroll
        for (int mt = 0; mt < 4; ++mt) {
            int row = mt * 16 + cl;
            #pragma unroll
            for (int kc = 0; kc < 4; ++kc) {
                f16x8 kf = *(const f16x8*)((const char*)Ks + row * 256 + (((kc * 4 + g) ^ (row & 7)) << 4));
                sacc[mt] = __builtin_amdgcn_mfma_f32_16x16x32_f16(qa[kc], kf, sacc[mt], 0, 0, 0);
            }
        }
        __builtin_amdgcn_s_setprio(0);

        // ---- online softmax (per 16-lane group; reg r <-> q-row 4g+r) ----
        float mnew[4], corr[4], psum[4];
        #pragma unroll
        for (int r = 0; r < 4; ++r) {
            float v = fmaxf(fmaxf(sacc[0][r], sacc[1][r]), fmaxf(sacc[2][r], sacc[3][r]));
            v = fmaxf(v, __shfl_xor(v, 1));
            v = fmaxf(v, __shfl_xor(v, 2));
            v = fmaxf(v, __shfl_xor(v, 4));
            v = fmaxf(v, __shfl_xor(v, 8));
            mnew[r] = fmaxf(mrun[r], v);
            corr[r] = __expf(mrun[r] - mnew[r]);
            mrun[r] = mnew[r];
            psum[r] = 0.f;
        }
        unsigned short* pw = Ps[w];
        #pragma unroll
        for (int mt = 0; mt < 4; ++mt) {
            #pragma unroll
            for (int r = 0; r < 4; ++r) {
                float p = __expf(sacc[mt][r] - mnew[r]);
                unsigned short pu = f2h(p);
                psum[r] += h2f(pu);   // denominator from rounded P (unbiased PV)
                int prow = 4 * g + r, pcol = mt * 16 + cl;
                *(unsigned short*)((char*)pw + prow * 128 + ((pcol * 2) ^ ((prow & 7) << 4))) = pu;
            }
        }
        #pragma unroll
        for (int r = 0; r < 4; ++r) {
            float s = psum[r];
            s += __shfl_xor(s, 1);
            s += __shfl_xor(s, 2);
            s += __shfl_xor(s, 4);
            s += __shfl_xor(s, 8);
            lrun[r] = lrun[r] * corr[r] + s;
        }
        #pragma unroll
        for (int it = 0; it < 8; ++it)
            #pragma unroll
            for (int r = 0; r < 4; ++r) yacc[it][r] *= corr[r];

        // ---- Y += P V ----
        f16x8 pa0 = *(const f16x8*)((const char*)pw + cl * 128 + ((g ^ (cl & 7)) << 4));
        f16x8 pa1 = *(const f16x8*)((const char*)pw + cl * 128 + (((4 + g) ^ (cl & 7)) << 4));
        __builtin_amdgcn_s_setprio(1);
        #pragma unroll
        for (int it = 0; it < 8; ++it) {
            int row = it * 16 + cl;
            f16x8 vf0 = *(const f16x8*)((const char*)Vs + row * 128 + ((g ^ (row & 7)) << 4));
            f16x8 vf1 = *(const f16x8*)((const char*)Vs + row * 128 + (((4 + g) ^ (row & 7)) << 4));
            yacc[it] = __builtin_amdgcn_mfma_f32_16x16x32_f16(pa0, vf0, yacc[it], 0, 0, 0);
            yacc[it] = __builtin_amdgcn_mfma_f32_16x16x32_f16(pa1, vf1, yacc[it], 0, 0, 0);
        }
        __builtin_amdgcn_s_setprio(0);
    }

    __syncthreads();   // all waves done reading Ks before we overwrite it

    // ---- normalize, park Y (fp16) in per-wave LDS, then DENSE 64B stores ----
    float rl[4];
    #pragma unroll
    for (int r = 0; r < 4; ++r) rl[r] = 1.0f / lrun[r];
    unsigned short* ys = Ks + w * (16 * 128);
    #pragma unroll
    for (int it = 0; it < 8; ++it)
        #pragma unroll
        for (int r = 0; r < 4; ++r)
            ys[(4 * g + r) * 128 + it * 16 + cl] = f2h(yacc[it][r] * rl[r]);
    // same-wave write->read; no barrier needed
    size_t rowbase = (size_t)((sp * BB + b) * NN + qr0 + w * 16);
    #pragma unroll
    for (int c = 0; c < 4; ++c) {
        int row = l >> 2;
        int seg = c * 4 + (l & 3);
        uint4 q = *(const uint4*)(ys + row * 128 + seg * 8);
        *(uint4*)(Yp + (rowbase + row) * II + seg * 8) = q;
    }
    if (cl == 0) {
        #pragma unroll
        for (int r = 0; r < 4; ++r) {
            float2 v; v.x = mrun[r]; v.y = lrun[r];
            ML[rowbase + 4 * g + r] = v;
        }
    }
}

// ---------------- combine partials + output conv + bias + residual ----------------
__global__ __launch_bounds__(256) void combine_kernel(
    const unsigned short* __restrict__ Yp, const float2* __restrict__ ML,
    const unsigned short* __restrict__ Wo, const float* __restrict__ b_out,
    const float* __restrict__ x, float* __restrict__ out)
{
    __shared__ unsigned short Ys[4][16 * 128];   // per-wave park, swizzled 256B rows

    int tid = threadIdx.x;
    int w = tid >> 6, l = tid & 63, g = l >> 4, cl = l & 15;
    int qt = blockIdx.x, b = blockIdx.y;
    int qr0 = qt * 64;
    int n = qr0 + w * 16 + cl;

    float ms[NSPLIT], ls[NSPLIT], wgt[NSPLIT];
    float M = -1e30f;
    #pragma unroll
    for (int s = 0; s < NSPLIT; ++s) {
        float2 ml = ML[(size_t)(s * BB + b) * NN + n];
        ms[s] = ml.x; ls[s] = ml.y;
        M = fmaxf(M, ml.x);
    }
    float wsum = 0.f;
    #pragma unroll
    for (int s = 0; s < NSPLIT; ++s) { wgt[s] = __expf(ms[s] - M) * ls[s]; wsum += wgt[s]; }
    float rd = 1.0f / wsum;
    #pragma unroll
    for (int s = 0; s < NSPLIT; ++s) wgt[s] *= rd;

    unsigned short* ys = Ys[w];
    #pragma unroll
    for (int j = 0; j < 4; ++j) {
        float acc[8];
        #pragma unroll
        for (int e = 0; e < 8; ++e) acc[e] = 0.f;
        #pragma unroll
        for (int s = 0; s < NSPLIT; ++s) {
            union { unsigned short s16[8]; uint4 q; } a;
            a.q = *(const uint4*)(Yp + ((size_t)(s * BB + b) * NN + n) * II + g * 32 + j * 8);
            #pragma unroll
            for (int e = 0; e < 8; ++e) acc[e] += wgt[s] * h2f(a.s16[e]);
        }
        union { unsigned short s16[8]; uint4 q; } o;
        #pragma unroll
        for (int e = 0; e < 8; ++e) o.s16[e] = f2h(acc[e]);
        *(uint4*)((char*)ys + cl * 256 + (((g * 4 + j) ^ (cl & 7)) << 4)) = o.q;
    }
    // same-wave write->read; no barrier needed

    f32x4 zero4 = {0.f, 0.f, 0.f, 0.f};
    f16x8 yf[4];
    #pragma unroll
    for (int kc = 0; kc < 4; ++kc)
        yf[kc] = *(const f16x8*)((const char*)ys + cl * 256 + (((kc * 4 + g) ^ (cl & 7)) << 4));
    for (int ct = 0; ct < 16; ++ct) {
        f32x4 oa = zero4;
        #pragma unroll
        for (int kc = 0; kc < 4; ++kc) {
            f16x8 wf = *(const f16x8*)(Wo + (ct * 16 + cl) * II + kc * 32 + g * 8);
            oa = __builtin_amdgcn_mfma_f32_16x16x32_f16(wf, yf[kc], oa, 0, 0, 0);
        }
        #pragma unroll
        for (int r = 0; r < 4; ++r) {
            int c = ct * 16 + 4 * g + r;
            size_t off = (size_t)(b * CC + c) * NN + n;
            out[off] = oa[r] + b_out[c] + x[off];
        }
    }
}

extern "C" void kernel_launch(void* const* d_in, const int* in_sizes, int n_in,
                              void* d_out, int out_size, void* d_ws, size_t ws_size,
                              hipStream_t stream) {
    const float* x     = (const float*)d_in[0];
    const float* w_g   = (const float*)d_in[1];
    const float* b_g   = (const float*)d_in[2];
    const float* w_th  = (const float*)d_in[3];
    const float* b_th  = (const float*)d_in[4];
    const float* w_ph  = (const float*)d_in[5];
    const float* b_ph  = (const float*)d_in[6];
    const float* w_out = (const float*)d_in[7];
    const float* b_o   = (const float*)d_in[8];
    float* out = (float*)d_out;

    const size_t SZ = (size_t)BB * NN * II;
    unsigned short* Qb = (unsigned short*)d_ws;
    unsigned short* Kb = Qb + SZ;
    unsigned short* Vt = Kb + SZ;
    unsigned short* Wo = Vt + SZ;
    unsigned short* Yp = Wo + (size_t)CC * II;                 // NSPLIT * SZ fp16
    float2*         ML = (float2*)(Yp + (size_t)NSPLIT * SZ);  // NSPLIT*B*N float2

    conv_wout_kernel<<<dim3((CC * II) / 256), dim3(256), 0, stream>>>(w_out, Wo);
    proj3_kernel<<<dim3(NN / 64, BB), dim3(256), 0, stream>>>(
        x, w_th, b_th, w_ph, b_ph, w_g, b_g, Qb, Kb, Vt);
    attn_kernel<<<dim3(NSPLIT * BB * (NN / 64)), dim3(256), 0, stream>>>(
        Qb, Kb, Vt, Yp, ML);
    combine_kernel<<<dim3(NN / 64, BB), dim3(256), 0, stream>>>(Yp, ML, Wo, b_o, x, out);
}

// Round 5
// 124.298 us; speedup vs baseline: 3.7612x; 2.1463x over previous
//
#include <hip/hip_runtime.h>

#define BB 4
#define CC 256
#define NN 4096
#define II 128
#define NSPLIT 4
#define KVH (NN / NSPLIT)   // 1024 KV rows per split
#define NT (KVH / 64)       // 16 tiles per split
#define LOG2E 1.4426950408889634f

typedef float f32x4 __attribute__((ext_vector_type(4)));
typedef _Float16 f16x8 __attribute__((ext_vector_type(8)));

static __device__ __forceinline__ unsigned short f2h(float f) {
    _Float16 h = (_Float16)f;
    return __builtin_bit_cast(unsigned short, h);
}
static __device__ __forceinline__ float h2f(unsigned short s) {
    return (float)__builtin_bit_cast(_Float16, s);
}
static __device__ __forceinline__ unsigned int pack2h(float a, float b) {
    return (unsigned int)f2h(a) | ((unsigned int)f2h(b) << 16);
}

// ---------------- w_out f32 -> fp16 ----------------
__global__ void conv_wout_kernel(const float* __restrict__ w, unsigned short* __restrict__ o) {
    int i = blockIdx.x * 256 + threadIdx.x;   // grid covers CC*II
    o[i] = f2h(w[i]);
}

// ---------------- MFMA projection: one (mat, batch, 64-n strip) per block ----------------
// out[i][n] = sum_c w[i][c] x[b][c][n] + bias[i];  mat0->Q (scaled by log2e), mat1->K, mat2->V^T
__global__ __launch_bounds__(256) void proj_kernel(
    const float* __restrict__ x,
    const float* __restrict__ w_th, const float* __restrict__ b_th,
    const float* __restrict__ w_ph, const float* __restrict__ b_ph,
    const float* __restrict__ w_g,  const float* __restrict__ b_g,
    unsigned short* __restrict__ Qb, unsigned short* __restrict__ Kb,
    unsigned short* __restrict__ Vt)
{
    __shared__ char lds[24576];
    unsigned short* wl = (unsigned short*)lds;            // [128 i][64 c] fp16, 128B rows, swz
    unsigned short* xl = (unsigned short*)(lds + 16384);  // [64 n][64 c]  fp16, 128B rows, swz

    int tid = threadIdx.x;
    int w = tid >> 6, l = tid & 63, g = l >> 4, cl = l & 15;
    int mat = blockIdx.z, b = blockIdx.y, n0 = blockIdx.x * 64;
    const float* wp = (mat == 0) ? w_th : (mat == 1) ? w_ph : w_g;
    const float* bp = (mat == 0) ? b_th : (mat == 1) ? b_ph : b_g;

    f32x4 acc[2][4];
    #pragma unroll
    for (int it = 0; it < 2; ++it)
        #pragma unroll
        for (int nt = 0; nt < 4; ++nt) acc[it][nt] = (f32x4){0.f, 0.f, 0.f, 0.f};

    const float* xb = x + (size_t)b * CC * NN;
    int c2 = tid >> 3, nch = tid & 7;   // x-staging: c-pair, n-chunk

    for (int c0 = 0; c0 < CC; c0 += 64) {
        __syncthreads();
        // stage w chunk [128 i][64 c] -> fp16
        #pragma unroll
        for (int r = 0; r < 4; ++r) {
            int idx = r * 256 + tid;
            int row = idx >> 3, ch = idx & 7;
            const float* src = wp + row * CC + c0 + ch * 8;
            float4 a = *(const float4*)src;
            float4 bq = *(const float4*)(src + 4);
            union { unsigned short s[8]; uint4 q; } pk;
            pk.s[0] = f2h(a.x); pk.s[1] = f2h(a.y); pk.s[2] = f2h(a.z); pk.s[3] = f2h(a.w);
            pk.s[4] = f2h(bq.x); pk.s[5] = f2h(bq.y); pk.s[6] = f2h(bq.z); pk.s[7] = f2h(bq.w);
            *(uint4*)((char*)wl + row * 128 + ((ch ^ (row & 7)) << 4)) = pk.q;
        }
        // stage x chunk transposed -> [64 n][64 c] fp16 (2 c-rows packed per b32)
        {
            const float* xsrc = xb + (size_t)(c0 + c2 * 2) * NN + n0 + nch * 8;
            float4 x00 = *(const float4*)xsrc;
            float4 x01 = *(const float4*)(xsrc + 4);
            float4 x10 = *(const float4*)(xsrc + NN);
            float4 x11 = *(const float4*)(xsrc + NN + 4);
            float lo[8] = {x00.x, x00.y, x00.z, x00.w, x01.x, x01.y, x01.z, x01.w};
            float hi[8] = {x10.x, x10.y, x10.z, x10.w, x11.x, x11.y, x11.z, x11.w};
            #pragma unroll
            for (int t = 0; t < 8; ++t) {
                int n = nch * 8 + t;
                *(unsigned int*)((char*)xl + n * 128 + ((c2 * 4) ^ ((n & 7) << 4))) = pack2h(lo[t], hi[t]);
            }
        }
        __syncthreads();
        // MFMA: wave covers i in [w*32, w*32+32)
        #pragma unroll
        for (int kc = 0; kc < 2; ++kc) {
            f16x8 af[2], bf[4];
            #pragma unroll
            for (int it = 0; it < 2; ++it) {
                int row = w * 32 + it * 16 + cl;
                af[it] = *(const f16x8*)((const char*)wl + row * 128 + (((kc * 4 + g) ^ (row & 7)) << 4));
            }
            #pragma unroll
            for (int nt = 0; nt < 4; ++nt) {
                int row = nt * 16 + cl;
                bf[nt] = *(const f16x8*)((const char*)xl + row * 128 + (((kc * 4 + g) ^ (row & 7)) << 4));
            }
            #pragma unroll
            for (int it = 0; it < 2; ++it)
                #pragma unroll
                for (int nt = 0; nt < 4; ++nt)
                    acc[it][nt] = __builtin_amdgcn_mfma_f32_16x16x32_f16(af[it], bf[nt], acc[it][nt], 0, 0, 0);
        }
    }

    // bias per lane-row
    float bv[2][4];
    #pragma unroll
    for (int it = 0; it < 2; ++it)
        #pragma unroll
        for (int r = 0; r < 4; ++r) bv[it][r] = bp[w * 32 + it * 16 + 4 * g + r];
    float scale = (mat == 0) ? LOG2E : 1.0f;

    __syncthreads();
    if (mat < 2) {
        // park [64 n][128 i] fp16 (256B rows, swz), then dense n-major stores
        unsigned short* pk = (unsigned short*)lds;
        #pragma unroll
        for (int it = 0; it < 2; ++it)
            #pragma unroll
            for (int nt = 0; nt < 4; ++nt)
                #pragma unroll
                for (int r = 0; r < 4; r += 2) {
                    int n = nt * 16 + cl;
                    int i = w * 32 + it * 16 + 4 * g + r;
                    unsigned int v = pack2h((acc[it][nt][r] + bv[it][r]) * scale,
                                            (acc[it][nt][r + 1] + bv[it][r + 1]) * scale);
                    *(unsigned int*)((char*)pk + n * 256 + ((i * 2) ^ ((n & 7) << 4))) = v;
                }
        __syncthreads();
        unsigned short* out = (mat == 0) ? Qb : Kb;
        #pragma unroll
        for (int r = 0; r < 4; ++r) {
            int idx = r * 256 + tid;
            int n = idx >> 4, seg = idx & 15;
            uint4 q = *(const uint4*)((const char*)pk + n * 256 + ((seg << 4) ^ ((n & 7) << 4)));
            *(uint4*)(out + (size_t)(b * NN + n0 + n) * II + seg * 8) = q;
        }
    } else {
        // park [128 i][64 n] fp16 (128B rows, swz), then dense i-major stores
        unsigned short* pk = (unsigned short*)lds;
        #pragma unroll
        for (int it = 0; it < 2; ++it)
            #pragma unroll
            for (int nt = 0; nt < 4; ++nt)
                #pragma unroll
                for (int r = 0; r < 4; ++r) {
                    int i = w * 32 + it * 16 + 4 * g + r;
                    int n = nt * 16 + cl;
                    *(unsigned short*)((char*)pk + i * 128 + ((n * 2) ^ ((i & 7) << 4))) =
                        f2h(acc[it][nt][r] + bv[it][r]);
                }
        __syncthreads();
        #pragma unroll
        for (int r = 0; r < 4; ++r) {
            int idx = r * 256 + tid;
            int i = idx >> 3, seg = idx & 7;
            uint4 q = *(const uint4*)((const char*)pk + i * 128 + ((seg << 4) ^ ((i & 7) << 4)));
            *(uint4*)(Vt + (size_t)(b * II + i) * NN + n0 + seg * 8) = q;
        }
    }
}

// ---------------- flash attention: swapped-operand QK^T, reg-resident P ----------------
// grid 1024: comb = (id&7)*2 + ((id>>3)&1): b=comb>>2, sp=comb&3; qt=id>>4.
// S^T = mfma(K, Q): lane holds full k-column for q = lane&15 -> in-lane softmax,
// P^T packed in-register as the PV B-operand (V staged with permuted cols to match).
__global__ __launch_bounds__(256, 4) void attn_kernel(
    const unsigned short* __restrict__ Qb,   // [B][N][II] fp16 (pre-scaled by log2e)
    const unsigned short* __restrict__ Kb,   // [B][N][II] fp16
    const unsigned short* __restrict__ Vb,   // [B][II][N] fp16
    unsigned short* __restrict__ Yp,         // [NSPLIT][B][N][II] fp16 normalized partial
    float2* __restrict__ ML)                 // [NSPLIT][B][N] {m,l} (base-2 domain)
{
    __shared__ unsigned short Ks[64 * 128];   // [k][c] 256B rows, XOR-swizzled (16 KB)
    __shared__ unsigned short Vs[128 * 64];   // [i][col'(k)] 128B rows, XOR-swizzled (16 KB)

    int tid = threadIdx.x;
    int w = tid >> 6, l = tid & 63, g = l >> 4, cl = l & 15;
    int id = blockIdx.x;
    int comb = (id & 7) * 2 + ((id >> 3) & 1);
    int b = comb >> 2, sp = comb & 3, qt = id >> 4;
    int qr0 = qt * 64;
    int m_base = sp * KVH;

    // Q B-fragments (loop-invariant): col=q=cl, k-slot c = kc*32+g*8+j
    f16x8 qa[4];
    {
        const unsigned short* qrow = Qb + (size_t)(b * NN + qr0 + w * 16 + cl) * II;
        #pragma unroll
        for (int kc = 0; kc < 4; ++kc)
            qa[kc] = *(const f16x8*)(qrow + kc * 32 + g * 8);
    }

    f32x4 yacc[8];   // Y^T tiles: row i = it*16+4g+r, col q = cl
    #pragma unroll
    for (int it = 0; it < 8; ++it) yacc[it] = (f32x4){0.f, 0.f, 0.f, 0.f};
    float mrun = -1e30f, lrun = 0.f;

    const unsigned short* kb = Kb + (size_t)(b * NN + m_base) * II;
    const unsigned short* vb = Vb + (size_t)b * II * NN + m_base;
    int krow = tid >> 4, kch = tid & 15;
    int vrow = tid >> 3, vch = tid & 7;
    int kswz = (kch ^ (krow & 7)) << 4;
    int vsw = (vrow & 7) << 4;
    // V column-permute base (bytes): col'(k): [5]=k5,[4:3]=k[3:2],[2]=k4,[1:0]=k[1:0]
    int vc0 = ((vch >> 2) * 32 + (vch & 1) * 16 + ((vch >> 1) & 1) * 4) * 2;

    uint4 k0, k1, k2, k3, v0, v1, v2, v3;   // named regs (no PromoteAlloca)
    k0 = *(const uint4*)(kb + (size_t)(krow) * II + kch * 8);
    k1 = *(const uint4*)(kb + (size_t)(16 + krow) * II + kch * 8);
    k2 = *(const uint4*)(kb + (size_t)(32 + krow) * II + kch * 8);
    k3 = *(const uint4*)(kb + (size_t)(48 + krow) * II + kch * 8);
    v0 = *(const uint4*)(vb + (size_t)(vrow) * NN + vch * 8);
    v1 = *(const uint4*)(vb + (size_t)(32 + vrow) * NN + vch * 8);
    v2 = *(const uint4*)(vb + (size_t)(64 + vrow) * NN + vch * 8);
    v3 = *(const uint4*)(vb + (size_t)(96 + vrow) * NN + vch * 8);

    for (int t = 0; t < NT; ++t) {
        __syncthreads();
        // publish K tile
        *(uint4*)((char*)Ks + (krow) * 256 + kswz) = k0;
        *(uint4*)((char*)Ks + (16 + krow) * 256 + kswz) = k1;
        *(uint4*)((char*)Ks + (32 + krow) * 256 + kswz) = k2;
        *(uint4*)((char*)Ks + (48 + krow) * 256 + kswz) = k3;
        // publish V tile with column permutation (two 8B writes per uint4)
        {
            uint2 lo, hi;
            lo.x = v0.x; lo.y = v0.y; hi.x = v0.z; hi.y = v0.w;
            *(uint2*)((char*)Vs + (vrow) * 128 + (vc0 ^ vsw)) = lo;
            *(uint2*)((char*)Vs + (vrow) * 128 + ((vc0 + 16) ^ vsw)) = hi;
            lo.x = v1.x; lo.y = v1.y; hi.x = v1.z; hi.y = v1.w;
            *(uint2*)((char*)Vs + (32 + vrow) * 128 + (vc0 ^ vsw)) = lo;
            *(uint2*)((char*)Vs + (32 + vrow) * 128 + ((vc0 + 16) ^ vsw)) = hi;
            lo.x = v2.x; lo.y = v2.y; hi.x = v2.z; hi.y = v2.w;
            *(uint2*)((char*)Vs + (64 + vrow) * 128 + (vc0 ^ vsw)) = lo;
            *(uint2*)((char*)Vs + (64 + vrow) * 128 + ((vc0 + 16) ^ vsw)) = hi;
            lo.x = v3.x; lo.y = v3.y; hi.x = v3.z; hi.y = v3.w;
            *(uint2*)((char*)Vs + (96 + vrow) * 128 + (vc0 ^ vsw)) = lo;
            *(uint2*)((char*)Vs + (96 + vrow) * 128 + ((vc0 + 16) ^ vsw)) = hi;
        }
        __syncthreads();
        // prefetch next tile
        if (t + 1 < NT) {
            const unsigned short* kp = kb + (size_t)(t + 1) * 64 * II;
            const unsigned short* vp = vb + (size_t)(t + 1) * 64;
            k0 = *(const uint4*)(kp + (size_t)(krow) * II + kch * 8);
            k1 = *(const uint4*)(kp + (size_t)(16 + krow) * II + kch * 8);
            k2 = *(const uint4*)(kp + (size_t)(32 + krow) * II + kch * 8);
            k3 = *(const uint4*)(kp + (size_t)(48 + krow) * II + kch * 8);
            v0 = *(const uint4*)(vp + (size_t)(vrow) * NN + vch * 8);
            v1 = *(const uint4*)(vp + (size_t)(32 + vrow) * NN + vch * 8);
            v2 = *(const uint4*)(vp + (size_t)(64 + vrow) * NN + vch * 8);
            v3 = *(const uint4*)(vp + (size_t)(96 + vrow) * NN + vch * 8);
        }

        // ---- S^T = K Q^T : lane holds S^T[k=mt*16+4g+r][q=cl] ----
        f32x4 sacc[4];
        #pragma unroll
        for (int mt = 0; mt < 4; ++mt) sacc[mt] = (f32x4){0.f, 0.f, 0.f, 0.f};
        __builtin_amdgcn_s_setprio(1);
        #pragma unroll
        for (int mt = 0; mt < 4; ++mt) {
            int row = mt * 16 + cl;
            #pragma unroll
            for (int kc = 0; kc < 4; ++kc) {
                f16x8 kf = *(const f16x8*)((const char*)Ks + row * 256 + (((kc * 4 + g) ^ (row & 7)) << 4));
                sacc[mt] = __builtin_amdgcn_mfma_f32_16x16x32_f16(kf, qa[kc], sacc[mt], 0, 0, 0);
            }
        }
        __builtin_amdgcn_s_setprio(0);

        // ---- in-lane online softmax (base-2) ----
        float tmax = fmaxf(fmaxf(fmaxf(sacc[0][0], sacc[0][1]), fmaxf(sacc[0][2], sacc[0][3])),
                           fmaxf(fmaxf(sacc[1][0], sacc[1][1]), fmaxf(sacc[1][2], sacc[1][3])));
        tmax = fmaxf(tmax, fmaxf(fmaxf(fmaxf(sacc[2][0], sacc[2][1]), fmaxf(sacc[2][2], sacc[2][3])),
                                 fmaxf(fmaxf(sacc[3][0], sacc[3][1]), fmaxf(sacc[3][2], sacc[3][3]))));
        tmax = fmaxf(tmax, __shfl_xor(tmax, 16));
        tmax = fmaxf(tmax, __shfl_xor(tmax, 32));
        float mnew = fmaxf(mrun, tmax);
        float corr = exp2f(mrun - mnew);
        mrun = mnew;

        // P^T -> fp16, packed directly as PV B-fragments (k_pv = (2kc+(j>>2))*16+4g+(j&3))
        union { _Float16 h[8]; f16x8 v; } pb0, pb1;
        float ps = 0.f;
        #pragma unroll
        for (int j = 0; j < 8; ++j) {
            float p0 = exp2f(sacc[j >> 2][j & 3] - mnew);
            float p1 = exp2f(sacc[2 + (j >> 2)][j & 3] - mnew);
            _Float16 h0 = (_Float16)p0, h1 = (_Float16)p1;
            ps += (float)h0 + (float)h1;
            pb0.h[j] = h0; pb1.h[j] = h1;
        }
        ps += __shfl_xor(ps, 16);
        ps += __shfl_xor(ps, 32);
        lrun = lrun * corr + ps;
        #pragma unroll
        for (int it = 0; it < 8; ++it)
            #pragma unroll
            for (int r = 0; r < 4; ++r) yacc[it][r] *= corr;

        // ---- Y^T += V^T P^T : A=V (rows i, permuted cols), B=P^T (regs) ----
        __builtin_amdgcn_s_setprio(1);
        #pragma unroll
        for (int it = 0; it < 8; ++it) {
            int row = it * 16 + cl;
            f16x8 vf0 = *(const f16x8*)((const char*)Vs + row * 128 + ((g ^ (row & 7)) << 4));
            f16x8 vf1 = *(const f16x8*)((const char*)Vs + row * 128 + (((4 + g) ^ (row & 7)) << 4));
            yacc[it] = __builtin_amdgcn_mfma_f32_16x16x32_f16(vf0, pb0.v, yacc[it], 0, 0, 0);
            yacc[it] = __builtin_amdgcn_mfma_f32_16x16x32_f16(vf1, pb1.v, yacc[it], 0, 0, 0);
        }
        __builtin_amdgcn_s_setprio(0);
    }

    __syncthreads();   // all waves done reading Ks/Vs

    // ---- normalize, park Y (fp16) per-wave in Ks, dense stores ----
    float rl = 1.0f / lrun;
    unsigned short* ys = Ks + w * (16 * 128);   // [q-local 16][i 128], 256B rows, swz
    #pragma unroll
    for (int it = 0; it < 8; ++it)
        #pragma unroll
        for (int r = 0; r < 4; r += 2) {
            int i = it * 16 + 4 * g + r;
            unsigned int v = pack2h(yacc[it][r] * rl, yacc[it][r + 1] * rl);
            *(unsigned int*)((char*)ys + cl * 256 + ((i * 2) ^ ((cl & 7) << 4))) = v;
        }
    // same-wave write->read; no barrier needed
    size_t rowbase = (size_t)((sp * BB + b) * NN + qr0 + w * 16);
    int prow = l >> 2;
    #pragma unroll
    for (int c = 0; c < 4; ++c) {
        int seg = c * 4 + (l & 3);
        uint4 q = *(const uint4*)((const char*)ys + prow * 256 + ((seg << 4) ^ ((prow & 7) << 4)));
        *(uint4*)(Yp + (rowbase + prow) * II + seg * 8) = q;
    }
    if (l < 16) {
        float2 v; v.x = mrun; v.y = lrun;
        ML[rowbase + l] = v;
    }
}

// ---------------- combine partials + output conv + bias + residual ----------------
__global__ __launch_bounds__(256) void combine_kernel(
    const unsigned short* __restrict__ Yp, const float2* __restrict__ ML,
    const unsigned short* __restrict__ Wo, const float* __restrict__ b_out,
    const float* __restrict__ x, float* __restrict__ out)
{
    __shared__ unsigned short Ys[4][16 * 128];   // per-wave park, swizzled 256B rows

    int tid = threadIdx.x;
    int w = tid >> 6, l = tid & 63, g = l >> 4, cl = l & 15;
    int qt = blockIdx.x, b = blockIdx.y;
    int qr0 = qt * 64;
    int n = qr0 + w * 16 + cl;

    float ms[NSPLIT], ls[NSPLIT], wgt[NSPLIT];
    float M = -1e30f;
    #pragma unroll
    for (int s = 0; s < NSPLIT; ++s) {
        float2 ml = ML[(size_t)(s * BB + b) * NN + n];
        ms[s] = ml.x; ls[s] = ml.y;
        M = fmaxf(M, ml.x);
    }
    float wsum = 0.f;
    #pragma unroll
    for (int s = 0; s < NSPLIT; ++s) { wgt[s] = exp2f(ms[s] - M) * ls[s]; wsum += wgt[s]; }
    float rd = 1.0f / wsum;
    #pragma unroll
    for (int s = 0; s < NSPLIT; ++s) wgt[s] *= rd;

    unsigned short* ys = Ys[w];
    #pragma unroll
    for (int j = 0; j < 4; ++j) {
        float acc[8];
        #pragma unroll
        for (int e = 0; e < 8; ++e) acc[e] = 0.f;
        #pragma unroll
        for (int s = 0; s < NSPLIT; ++s) {
            union { unsigned short s16[8]; uint4 q; } a;
            a.q = *(const uint4*)(Yp + ((size_t)(s * BB + b) * NN + n) * II + g * 32 + j * 8);
            #pragma unroll
            for (int e = 0; e < 8; ++e) acc[e] += wgt[s] * h2f(a.s16[e]);
        }
        union { unsigned short s16[8]; uint4 q; } o;
        #pragma unroll
        for (int e = 0; e < 8; ++e) o.s16[e] = f2h(acc[e]);
        *(uint4*)((char*)ys + cl * 256 + (((g * 4 + j) ^ (cl & 7)) << 4)) = o.q;
    }
    // same-wave write->read; no barrier needed

    f32x4 zero4 = {0.f, 0.f, 0.f, 0.f};
    f16x8 yf[4];
    #pragma unroll
    for (int kc = 0; kc < 4; ++kc)
        yf[kc] = *(const f16x8*)((const char*)ys + cl * 256 + (((kc * 4 + g) ^ (cl & 7)) << 4));
    for (int ct = 0; ct < 16; ++ct) {
        f32x4 oa = zero4;
        #pragma unroll
        for (int kc = 0; kc < 4; ++kc) {
            f16x8 wf = *(const f16x8*)(Wo + (ct * 16 + cl) * II + kc * 32 + g * 8);
            oa = __builtin_amdgcn_mfma_f32_16x16x32_f16(wf, yf[kc], oa, 0, 0, 0);
        }
        #pragma unroll
        for (int r = 0; r < 4; ++r) {
            int c = ct * 16 + 4 * g + r;
            size_t off = (size_t)(b * CC + c) * NN + n;
            out[off] = oa[r] + b_out[c] + x[off];
        }
    }
}

extern "C" void kernel_launch(void* const* d_in, const int* in_sizes, int n_in,
                              void* d_out, int out_size, void* d_ws, size_t ws_size,
                              hipStream_t stream) {
    const float* x     = (const float*)d_in[0];
    const float* w_g   = (const float*)d_in[1];
    const float* b_g   = (const float*)d_in[2];
    const float* w_th  = (const float*)d_in[3];
    const float* b_th  = (const float*)d_in[4];
    const float* w_ph  = (const float*)d_in[5];
    const float* b_ph  = (const float*)d_in[6];
    const float* w_out = (const float*)d_in[7];
    const float* b_o   = (const float*)d_in[8];
    float* out = (float*)d_out;

    const size_t SZ = (size_t)BB * NN * II;
    unsigned short* Qb = (unsigned short*)d_ws;
    unsigned short* Kb = Qb + SZ;
    unsigned short* Vt = Kb + SZ;
    unsigned short* Wo = Vt + SZ;
    unsigned short* Yp = Wo + (size_t)CC * II;                 // NSPLIT * SZ fp16
    float2*         ML = (float2*)(Yp + (size_t)NSPLIT * SZ);  // NSPLIT*B*N float2

    conv_wout_kernel<<<dim3((CC * II) / 256), dim3(256), 0, stream>>>(w_out, Wo);
    proj_kernel<<<dim3(NN / 64, BB, 3), dim3(256), 0, stream>>>(
        x, w_th, b_th, w_ph, b_ph, w_g, b_g, Qb, Kb, Vt);
    attn_kernel<<<dim3(NSPLIT * BB * (NN / 64)), dim3(256), 0, stream>>>(
        Qb, Kb, Vt, Yp, ML);
    combine_kernel<<<dim3(NN / 64, BB), dim3(256), 0, stream>>>(Yp, ML, Wo, b_o, x, out);
}

// Round 6
// 109.222 us; speedup vs baseline: 4.2803x; 1.1380x over previous
//
#include <hip/hip_runtime.h>

#define BB 4
#define CC 256
#define NN 4096
#define II 128
#define NSPLIT 4
#define KVH (NN / NSPLIT)   // 1024 KV rows per split
#define NT (KVH / 64)       // 16 tiles per split
#define LOG2E 1.4426950408889634f

typedef float f32x4 __attribute__((ext_vector_type(4)));
typedef _Float16 f16x8 __attribute__((ext_vector_type(8)));

static __device__ __forceinline__ unsigned short f2h(float f) {
    _Float16 h = (_Float16)f;
    return __builtin_bit_cast(unsigned short, h);
}
static __device__ __forceinline__ float h2f(unsigned short s) {
    return (float)__builtin_bit_cast(_Float16, s);
}
static __device__ __forceinline__ unsigned int pack2h(float a, float b) {
    return (unsigned int)f2h(a) | ((unsigned int)f2h(b) << 16);
}

// ---------------- w_out f32 -> fp16 ----------------
__global__ void conv_wout_kernel(const float* __restrict__ w, unsigned short* __restrict__ o) {
    int i = blockIdx.x * 256 + threadIdx.x;   // grid covers CC*II
    o[i] = f2h(w[i]);
}

// ---------------- MFMA projection: one (mat, batch, 64-n strip) per block ----------------
__global__ __launch_bounds__(256) void proj_kernel(
    const float* __restrict__ x,
    const float* __restrict__ w_th, const float* __restrict__ b_th,
    const float* __restrict__ w_ph, const float* __restrict__ b_ph,
    const float* __restrict__ w_g,  const float* __restrict__ b_g,
    unsigned short* __restrict__ Qb, unsigned short* __restrict__ Kb,
    unsigned short* __restrict__ Vt)
{
    __shared__ char lds[24576];
    unsigned short* wl = (unsigned short*)lds;            // [128 i][64 c] fp16, 128B rows, swz
    unsigned short* xl = (unsigned short*)(lds + 16384);  // [64 n][64 c]  fp16, 128B rows, swz

    int tid = threadIdx.x;
    int w = tid >> 6, l = tid & 63, g = l >> 4, cl = l & 15;
    int mat = blockIdx.z, b = blockIdx.y, n0 = blockIdx.x * 64;
    const float* wp = (mat == 0) ? w_th : (mat == 1) ? w_ph : w_g;
    const float* bp = (mat == 0) ? b_th : (mat == 1) ? b_ph : b_g;

    f32x4 acc[2][4];
    #pragma unroll
    for (int it = 0; it < 2; ++it)
        #pragma unroll
        for (int nt = 0; nt < 4; ++nt) acc[it][nt] = (f32x4){0.f, 0.f, 0.f, 0.f};

    const float* xb = x + (size_t)b * CC * NN;
    int c2 = tid >> 3, nch = tid & 7;   // x-staging: c-pair, n-chunk

    for (int c0 = 0; c0 < CC; c0 += 64) {
        __syncthreads();
        #pragma unroll
        for (int r = 0; r < 4; ++r) {
            int idx = r * 256 + tid;
            int row = idx >> 3, ch = idx & 7;
            const float* src = wp + row * CC + c0 + ch * 8;
            float4 a = *(const float4*)src;
            float4 bq = *(const float4*)(src + 4);
            union { unsigned short s[8]; uint4 q; } pk;
            pk.s[0] = f2h(a.x); pk.s[1] = f2h(a.y); pk.s[2] = f2h(a.z); pk.s[3] = f2h(a.w);
            pk.s[4] = f2h(bq.x); pk.s[5] = f2h(bq.y); pk.s[6] = f2h(bq.z); pk.s[7] = f2h(bq.w);
            *(uint4*)((char*)wl + row * 128 + ((ch ^ (row & 7)) << 4)) = pk.q;
        }
        {
            const float* xsrc = xb + (size_t)(c0 + c2 * 2) * NN + n0 + nch * 8;
            float4 x00 = *(const float4*)xsrc;
            float4 x01 = *(const float4*)(xsrc + 4);
            float4 x10 = *(const float4*)(xsrc + NN);
            float4 x11 = *(const float4*)(xsrc + NN + 4);
            float lo[8] = {x00.x, x00.y, x00.z, x00.w, x01.x, x01.y, x01.z, x01.w};
            float hi[8] = {x10.x, x10.y, x10.z, x10.w, x11.x, x11.y, x11.z, x11.w};
            #pragma unroll
            for (int t = 0; t < 8; ++t) {
                int n = nch * 8 + t;
                *(unsigned int*)((char*)xl + n * 128 + ((c2 * 4) ^ ((n & 7) << 4))) = pack2h(lo[t], hi[t]);
            }
        }
        __syncthreads();
        #pragma unroll
        for (int kc = 0; kc < 2; ++kc) {
            f16x8 af[2], bf[4];
            #pragma unroll
            for (int it = 0; it < 2; ++it) {
                int row = w * 32 + it * 16 + cl;
                af[it] = *(const f16x8*)((const char*)wl + row * 128 + (((kc * 4 + g) ^ (row & 7)) << 4));
            }
            #pragma unroll
            for (int nt = 0; nt < 4; ++nt) {
                int row = nt * 16 + cl;
                bf[nt] = *(const f16x8*)((const char*)xl + row * 128 + (((kc * 4 + g) ^ (row & 7)) << 4));
            }
            #pragma unroll
            for (int it = 0; it < 2; ++it)
                #pragma unroll
                for (int nt = 0; nt < 4; ++nt)
                    acc[it][nt] = __builtin_amdgcn_mfma_f32_16x16x32_f16(af[it], bf[nt], acc[it][nt], 0, 0, 0);
        }
    }

    float bv[2][4];
    #pragma unroll
    for (int it = 0; it < 2; ++it)
        #pragma unroll
        for (int r = 0; r < 4; ++r) bv[it][r] = bp[w * 32 + it * 16 + 4 * g + r];
    float scale = (mat == 0) ? LOG2E : 1.0f;

    __syncthreads();
    if (mat < 2) {
        unsigned short* pk = (unsigned short*)lds;
        #pragma unroll
        for (int it = 0; it < 2; ++it)
            #pragma unroll
            for (int nt = 0; nt < 4; ++nt)
                #pragma unroll
                for (int r = 0; r < 4; r += 2) {
                    int n = nt * 16 + cl;
                    int i = w * 32 + it * 16 + 4 * g + r;
                    unsigned int v = pack2h((acc[it][nt][r] + bv[it][r]) * scale,
                                            (acc[it][nt][r + 1] + bv[it][r + 1]) * scale);
                    *(unsigned int*)((char*)pk + n * 256 + ((i * 2) ^ ((n & 7) << 4))) = v;
                }
        __syncthreads();
        unsigned short* out = (mat == 0) ? Qb : Kb;
        #pragma unroll
        for (int r = 0; r < 4; ++r) {
            int idx = r * 256 + tid;
            int n = idx >> 4, seg = idx & 15;
            uint4 q = *(const uint4*)((const char*)pk + n * 256 + ((seg << 4) ^ ((n & 7) << 4)));
            *(uint4*)(out + (size_t)(b * NN + n0 + n) * II + seg * 8) = q;
        }
    } else {
        unsigned short* pk = (unsigned short*)lds;
        #pragma unroll
        for (int it = 0; it < 2; ++it)
            #pragma unroll
            for (int nt = 0; nt < 4; ++nt)
                #pragma unroll
                for (int r = 0; r < 4; ++r) {
                    int i = w * 32 + it * 16 + 4 * g + r;
                    int n = nt * 16 + cl;
                    *(unsigned short*)((char*)pk + i * 128 + ((n * 2) ^ ((i & 7) << 4))) =
                        f2h(acc[it][nt][r] + bv[it][r]);
                }
        __syncthreads();
        #pragma unroll
        for (int r = 0; r < 4; ++r) {
            int idx = r * 256 + tid;
            int i = idx >> 3, seg = idx & 7;
            uint4 q = *(const uint4*)((const char*)pk + i * 128 + ((seg << 4) ^ ((i & 7) << 4)));
            *(uint4*)(Vt + (size_t)(b * II + i) * NN + n0 + seg * 8) = q;
        }
    }
}

// ---------------- flash attention: 32 q-rows per wave, shared K/V fragment reads ----------------
// grid 512: comb = (id&7)*2 + ((id>>3)&1): b=comb>>2, sp=comb&3; qt=id>>4 covers 128 q.
__global__ __launch_bounds__(256, 2) void attn_kernel(
    const unsigned short* __restrict__ Qb,   // [B][N][II] fp16 (pre-scaled by log2e)
    const unsigned short* __restrict__ Kb,   // [B][N][II] fp16
    const unsigned short* __restrict__ Vb,   // [B][II][N] fp16
    unsigned short* __restrict__ Yp,         // [NSPLIT][B][N][II] fp16 normalized partial
    float2* __restrict__ ML)                 // [NSPLIT][B][N] {m,l} (base-2 domain)
{
    __shared__ unsigned short Ks[64 * 128];   // [k][c] 256B rows, XOR-swizzled (16 KB)
    __shared__ unsigned short Vs[128 * 64];   // [i][col'(k)] 128B rows, XOR-swizzled (16 KB)

    int tid = threadIdx.x;
    int w = tid >> 6, l = tid & 63, g = l >> 4, cl = l & 15;
    int id = blockIdx.x;
    int comb = (id & 7) * 2 + ((id >> 3) & 1);
    int b = comb >> 2, sp = comb & 3, qt = id >> 4;
    int qr0 = qt * 128;
    int m_base = sp * KVH;

    // Q B-fragments for the wave's two 16-q groups
    f16x8 qa0[4], qa1[4];
    {
        const unsigned short* qrow0 = Qb + (size_t)(b * NN + qr0 + w * 32 + cl) * II;
        const unsigned short* qrow1 = qrow0 + 16 * II;
        #pragma unroll
        for (int kc = 0; kc < 4; ++kc) {
            qa0[kc] = *(const f16x8*)(qrow0 + kc * 32 + g * 8);
            qa1[kc] = *(const f16x8*)(qrow1 + kc * 32 + g * 8);
        }
    }

    f32x4 yacc0[8], yacc1[8];
    #pragma unroll
    for (int it = 0; it < 8; ++it) {
        yacc0[it] = (f32x4){0.f, 0.f, 0.f, 0.f};
        yacc1[it] = (f32x4){0.f, 0.f, 0.f, 0.f};
    }
    float mrun0 = -1e30f, lrun0 = 0.f, mrun1 = -1e30f, lrun1 = 0.f;

    const unsigned short* kb = Kb + (size_t)(b * NN + m_base) * II;
    const unsigned short* vb = Vb + (size_t)b * II * NN + m_base;
    int krow = tid >> 4, kch = tid & 15;
    int vrow = tid >> 3, vch = tid & 7;
    int kswz = (kch ^ (krow & 7)) << 4;
    int vsw = (vrow & 7) << 4;
    int vc0 = ((vch >> 2) * 32 + (vch & 1) * 16 + ((vch >> 1) & 1) * 4) * 2;

    uint4 k0, k1, k2, k3, v0, v1, v2, v3;   // named regs (no PromoteAlloca)
    k0 = *(const uint4*)(kb + (size_t)(krow) * II + kch * 8);
    k1 = *(const uint4*)(kb + (size_t)(16 + krow) * II + kch * 8);
    k2 = *(const uint4*)(kb + (size_t)(32 + krow) * II + kch * 8);
    k3 = *(const uint4*)(kb + (size_t)(48 + krow) * II + kch * 8);
    v0 = *(const uint4*)(vb + (size_t)(vrow) * NN + vch * 8);
    v1 = *(const uint4*)(vb + (size_t)(32 + vrow) * NN + vch * 8);
    v2 = *(const uint4*)(vb + (size_t)(64 + vrow) * NN + vch * 8);
    v3 = *(const uint4*)(vb + (size_t)(96 + vrow) * NN + vch * 8);

    for (int t = 0; t < NT; ++t) {
        __syncthreads();
        // publish K tile
        *(uint4*)((char*)Ks + (krow) * 256 + kswz) = k0;
        *(uint4*)((char*)Ks + (16 + krow) * 256 + kswz) = k1;
        *(uint4*)((char*)Ks + (32 + krow) * 256 + kswz) = k2;
        *(uint4*)((char*)Ks + (48 + krow) * 256 + kswz) = k3;
        // publish V tile with column permutation
        {
            uint2 lo, hi;
            lo.x = v0.x; lo.y = v0.y; hi.x = v0.z; hi.y = v0.w;
            *(uint2*)((char*)Vs + (vrow) * 128 + (vc0 ^ vsw)) = lo;
            *(uint2*)((char*)Vs + (vrow) * 128 + ((vc0 + 16) ^ vsw)) = hi;
            lo.x = v1.x; lo.y = v1.y; hi.x = v1.z; hi.y = v1.w;
            *(uint2*)((char*)Vs + (32 + vrow) * 128 + (vc0 ^ vsw)) = lo;
            *(uint2*)((char*)Vs + (32 + vrow) * 128 + ((vc0 + 16) ^ vsw)) = hi;
            lo.x = v2.x; lo.y = v2.y; hi.x = v2.z; hi.y = v2.w;
            *(uint2*)((char*)Vs + (64 + vrow) * 128 + (vc0 ^ vsw)) = lo;
            *(uint2*)((char*)Vs + (64 + vrow) * 128 + ((vc0 + 16) ^ vsw)) = hi;
            lo.x = v3.x; lo.y = v3.y; hi.x = v3.z; hi.y = v3.w;
            *(uint2*)((char*)Vs + (96 + vrow) * 128 + (vc0 ^ vsw)) = lo;
            *(uint2*)((char*)Vs + (96 + vrow) * 128 + ((vc0 + 16) ^ vsw)) = hi;
        }
        __syncthreads();
        // prefetch next K (latency hides under QK)
        if (t + 1 < NT) {
            const unsigned short* kp = kb + (size_t)(t + 1) * 64 * II;
            k0 = *(const uint4*)(kp + (size_t)(krow) * II + kch * 8);
            k1 = *(const uint4*)(kp + (size_t)(16 + krow) * II + kch * 8);
            k2 = *(const uint4*)(kp + (size_t)(32 + krow) * II + kch * 8);
            k3 = *(const uint4*)(kp + (size_t)(48 + krow) * II + kch * 8);
        }

        // ---- S^T = K Q^T for both q-groups, each K fragment read ONCE ----
        f32x4 s0[4], s1[4];
        #pragma unroll
        for (int mt = 0; mt < 4; ++mt) {
            s0[mt] = (f32x4){0.f, 0.f, 0.f, 0.f};
            s1[mt] = (f32x4){0.f, 0.f, 0.f, 0.f};
        }
        __builtin_amdgcn_s_setprio(1);
        #pragma unroll
        for (int mt = 0; mt < 4; ++mt) {
            int row = mt * 16 + cl;
            #pragma unroll
            for (int kc = 0; kc < 4; ++kc) {
                f16x8 kf = *(const f16x8*)((const char*)Ks + row * 256 + (((kc * 4 + g) ^ (row & 7)) << 4));
                s0[mt] = __builtin_amdgcn_mfma_f32_16x16x32_f16(kf, qa0[kc], s0[mt], 0, 0, 0);
                s1[mt] = __builtin_amdgcn_mfma_f32_16x16x32_f16(kf, qa1[kc], s1[mt], 0, 0, 0);
            }
        }
        __builtin_amdgcn_s_setprio(0);
        // prefetch next V (latency hides under softmax+PV)
        if (t + 1 < NT) {
            const unsigned short* vp = vb + (size_t)(t + 1) * 64;
            v0 = *(const uint4*)(vp + (size_t)(vrow) * NN + vch * 8);
            v1 = *(const uint4*)(vp + (size_t)(32 + vrow) * NN + vch * 8);
            v2 = *(const uint4*)(vp + (size_t)(64 + vrow) * NN + vch * 8);
            v3 = *(const uint4*)(vp + (size_t)(96 + vrow) * NN + vch * 8);
        }

        // ---- softmax q-group 0 (in-lane, base-2, defer-rescale) ----
        union { _Float16 h[8]; f16x8 v; } pb00, pb01, pb10, pb11;
        {
            float tmax = fmaxf(fmaxf(fmaxf(s0[0][0], s0[0][1]), fmaxf(s0[0][2], s0[0][3])),
                               fmaxf(fmaxf(s0[1][0], s0[1][1]), fmaxf(s0[1][2], s0[1][3])));
            tmax = fmaxf(tmax, fmaxf(fmaxf(fmaxf(s0[2][0], s0[2][1]), fmaxf(s0[2][2], s0[2][3])),
                                     fmaxf(fmaxf(s0[3][0], s0[3][1]), fmaxf(s0[3][2], s0[3][3]))));
            tmax = fmaxf(tmax, __shfl_xor(tmax, 16));
            tmax = fmaxf(tmax, __shfl_xor(tmax, 32));
            if (!__all(tmax <= mrun0 + 8.0f)) {
                float mnew = fmaxf(mrun0, tmax);
                float corr = exp2f(mrun0 - mnew);
                mrun0 = mnew;
                lrun0 *= corr;
                #pragma unroll
                for (int it = 0; it < 8; ++it)
                    #pragma unroll
                    for (int r = 0; r < 4; ++r) yacc0[it][r] *= corr;
            }
            float ps = 0.f;
            #pragma unroll
            for (int j = 0; j < 8; ++j) {
                float p0 = exp2f(s0[j >> 2][j & 3] - mrun0);
                float p1 = exp2f(s0[2 + (j >> 2)][j & 3] - mrun0);
                _Float16 h0 = (_Float16)p0, h1 = (_Float16)p1;
                ps += (float)h0 + (float)h1;
                pb00.h[j] = h0; pb01.h[j] = h1;
            }
            ps += __shfl_xor(ps, 16);
            ps += __shfl_xor(ps, 32);
            lrun0 += ps;
        }
        // ---- softmax q-group 1 ----
        {
            float tmax = fmaxf(fmaxf(fmaxf(s1[0][0], s1[0][1]), fmaxf(s1[0][2], s1[0][3])),
                               fmaxf(fmaxf(s1[1][0], s1[1][1]), fmaxf(s1[1][2], s1[1][3])));
            tmax = fmaxf(tmax, fmaxf(fmaxf(fmaxf(s1[2][0], s1[2][1]), fmaxf(s1[2][2], s1[2][3])),
                                     fmaxf(fmaxf(s1[3][0], s1[3][1]), fmaxf(s1[3][2], s1[3][3]))));
            tmax = fmaxf(tmax, __shfl_xor(tmax, 16));
            tmax = fmaxf(tmax, __shfl_xor(tmax, 32));
            if (!__all(tmax <= mrun1 + 8.0f)) {
                float mnew = fmaxf(mrun1, tmax);
                float corr = exp2f(mrun1 - mnew);
                mrun1 = mnew;
                lrun1 *= corr;
                #pragma unroll
                for (int it = 0; it < 8; ++it)
                    #pragma unroll
                    for (int r = 0; r < 4; ++r) yacc1[it][r] *= corr;
            }
            float ps = 0.f;
            #pragma unroll
            for (int j = 0; j < 8; ++j) {
                float p0 = exp2f(s1[j >> 2][j & 3] - mrun1);
                float p1 = exp2f(s1[2 + (j >> 2)][j & 3] - mrun1);
                _Float16 h0 = (_Float16)p0, h1 = (_Float16)p1;
                ps += (float)h0 + (float)h1;
                pb10.h[j] = h0; pb11.h[j] = h1;
            }
            ps += __shfl_xor(ps, 16);
            ps += __shfl_xor(ps, 32);
            lrun1 += ps;
        }

        // ---- Y^T += V^T P^T, each V fragment read ONCE, feeds both q-groups ----
        __builtin_amdgcn_s_setprio(1);
        #pragma unroll
        for (int it = 0; it < 8; ++it) {
            int row = it * 16 + cl;
            f16x8 vf0 = *(const f16x8*)((const char*)Vs + row * 128 + ((g ^ (row & 7)) << 4));
            f16x8 vf1 = *(const f16x8*)((const char*)Vs + row * 128 + (((4 + g) ^ (row & 7)) << 4));
            yacc0[it] = __builtin_amdgcn_mfma_f32_16x16x32_f16(vf0, pb00.v, yacc0[it], 0, 0, 0);
            yacc0[it] = __builtin_amdgcn_mfma_f32_16x16x32_f16(vf1, pb01.v, yacc0[it], 0, 0, 0);
            yacc1[it] = __builtin_amdgcn_mfma_f32_16x16x32_f16(vf0, pb10.v, yacc1[it], 0, 0, 0);
            yacc1[it] = __builtin_amdgcn_mfma_f32_16x16x32_f16(vf1, pb11.v, yacc1[it], 0, 0, 0);
        }
        __builtin_amdgcn_s_setprio(0);
    }

    __syncthreads();   // all waves done reading Ks/Vs

    // ---- normalize, park per wave in Ks, dense stores (per q-group) ----
    unsigned short* ys = Ks + w * 2048;   // [16 q][128 i], 256B rows, swz
    size_t rowbase0 = (size_t)((sp * BB + b) * NN + qr0 + w * 32);
    int prow = l >> 2;
    {
        float rl = 1.0f / lrun0;
        #pragma unroll
        for (int it = 0; it < 8; ++it)
            #pragma unroll
            for (int r = 0; r < 4; r += 2) {
                int i = it * 16 + 4 * g + r;
                *(unsigned int*)((char*)ys + cl * 256 + ((i * 2) ^ ((cl & 7) << 4))) =
                    pack2h(yacc0[it][r] * rl, yacc0[it][r + 1] * rl);
            }
        #pragma unroll
        for (int c = 0; c < 4; ++c) {
            int seg = c * 4 + (l & 3);
            uint4 q = *(const uint4*)((const char*)ys + prow * 256 + ((seg << 4) ^ ((prow & 7) << 4)));
            *(uint4*)(Yp + (rowbase0 + prow) * II + seg * 8) = q;
        }
    }
    {
        float rl = 1.0f / lrun1;
        #pragma unroll
        for (int it = 0; it < 8; ++it)
            #pragma unroll
            for (int r = 0; r < 4; r += 2) {
                int i = it * 16 + 4 * g + r;
                *(unsigned int*)((char*)ys + cl * 256 + ((i * 2) ^ ((cl & 7) << 4))) =
                    pack2h(yacc1[it][r] * rl, yacc1[it][r + 1] * rl);
            }
        #pragma unroll
        for (int c = 0; c < 4; ++c) {
            int seg = c * 4 + (l & 3);
            uint4 q = *(const uint4*)((const char*)ys + prow * 256 + ((seg << 4) ^ ((prow & 7) << 4)));
            *(uint4*)(Yp + (rowbase0 + 16 + prow) * II + seg * 8) = q;
        }
    }
    if (l < 16) {
        float2 v; v.x = mrun0; v.y = lrun0;
        ML[rowbase0 + l] = v;
    } else if (l < 32) {
        float2 v; v.x = mrun1; v.y = lrun1;
        ML[rowbase0 + 16 + (l - 16)] = v;
    }
}

// ---------------- combine partials + output conv + bias + residual ----------------
__global__ __launch_bounds__(256) void combine_kernel(
    const unsigned short* __restrict__ Yp, const float2* __restrict__ ML,
    const unsigned short* __restrict__ Wo, const float* __restrict__ b_out,
    const float* __restrict__ x, float* __restrict__ out)
{
    __shared__ unsigned short Ys[4][16 * 128];   // per-wave park, swizzled 256B rows

    int tid = threadIdx.x;
    int w = tid >> 6, l = tid & 63, g = l >> 4, cl = l & 15;
    int qt = blockIdx.x, b = blockIdx.y;
    int qr0 = qt * 64;
    int n = qr0 + w * 16 + cl;

    float ms[NSPLIT], ls[NSPLIT], wgt[NSPLIT];
    float M = -1e30f;
    #pragma unroll
    for (int s = 0; s < NSPLIT; ++s) {
        float2 ml = ML[(size_t)(s * BB + b) * NN + n];
        ms[s] = ml.x; ls[s] = ml.y;
        M = fmaxf(M, ml.x);
    }
    float wsum = 0.f;
    #pragma unroll
    for (int s = 0; s < NSPLIT; ++s) { wgt[s] = exp2f(ms[s] - M) * ls[s]; wsum += wgt[s]; }
    float rd = 1.0f / wsum;
    #pragma unroll
    for (int s = 0; s < NSPLIT; ++s) wgt[s] *= rd;

    unsigned short* ys = Ys[w];
    #pragma unroll
    for (int j = 0; j < 4; ++j) {
        float acc[8];
        #pragma unroll
        for (int e = 0; e < 8; ++e) acc[e] = 0.f;
        #pragma unroll
        for (int s = 0; s < NSPLIT; ++s) {
            union { unsigned short s16[8]; uint4 q; } a;
            a.q = *(const uint4*)(Yp + ((size_t)(s * BB + b) * NN + n) * II + g * 32 + j * 8);
            #pragma unroll
            for (int e = 0; e < 8; ++e) acc[e] += wgt[s] * h2f(a.s16[e]);
        }
        union { unsigned short s16[8]; uint4 q; } o;
        #pragma unroll
        for (int e = 0; e < 8; ++e) o.s16[e] = f2h(acc[e]);
        *(uint4*)((char*)ys + cl * 256 + (((g * 4 + j) ^ (cl & 7)) << 4)) = o.q;
    }
    // same-wave write->read; no barrier needed

    f32x4 zero4 = {0.f, 0.f, 0.f, 0.f};
    f16x8 yf[4];
    #pragma unroll
    for (int kc = 0; kc < 4; ++kc)
        yf[kc] = *(const f16x8*)((const char*)ys + cl * 256 + (((kc * 4 + g) ^ (cl & 7)) << 4));
    for (int ct = 0; ct < 16; ++ct) {
        f32x4 oa = zero4;
        #pragma unroll
        for (int kc = 0; kc < 4; ++kc) {
            f16x8 wf = *(const f16x8*)(Wo + (ct * 16 + cl) * II + kc * 32 + g * 8);
            oa = __builtin_amdgcn_mfma_f32_16x16x32_f16(wf, yf[kc], oa, 0, 0, 0);
        }
        #pragma unroll
        for (int r = 0; r < 4; ++r) {
            int c = ct * 16 + 4 * g + r;
            size_t off = (size_t)(b * CC + c) * NN + n;
            out[off] = oa[r] + b_out[c] + x[off];
        }
    }
}

extern "C" void kernel_launch(void* const* d_in, const int* in_sizes, int n_in,
                              void* d_out, int out_size, void* d_ws, size_t ws_size,
                              hipStream_t stream) {
    const float* x     = (const float*)d_in[0];
    const float* w_g   = (const float*)d_in[1];
    const float* b_g   = (const float*)d_in[2];
    const float* w_th  = (const float*)d_in[3];
    const float* b_th  = (const float*)d_in[4];
    const float* w_ph  = (const float*)d_in[5];
    const float* b_ph  = (const float*)d_in[6];
    const float* w_out = (const float*)d_in[7];
    const float* b_o   = (const float*)d_in[8];
    float* out = (float*)d_out;

    const size_t SZ = (size_t)BB * NN * II;
    unsigned short* Qb = (unsigned short*)d_ws;
    unsigned short* Kb = Qb + SZ;
    unsigned short* Vt = Kb + SZ;
    unsigned short* Wo = Vt + SZ;
    unsigned short* Yp = Wo + (size_t)CC * II;                 // NSPLIT * SZ fp16
    float2*         ML = (float2*)(Yp + (size_t)NSPLIT * SZ);  // NSPLIT*B*N float2

    conv_wout_kernel<<<dim3((CC * II) / 256), dim3(256), 0, stream>>>(w_out, Wo);
    proj_kernel<<<dim3(NN / 64, BB, 3), dim3(256), 0, stream>>>(
        x, w_th, b_th, w_ph, b_ph, w_g, b_g, Qb, Kb, Vt);
    attn_kernel<<<dim3(NSPLIT * BB * (NN / 128)), dim3(256), 0, stream>>>(
        Qb, Kb, Vt, Yp, ML);
    combine_kernel<<<dim3(NN / 64, BB), dim3(256), 0, stream>>>(Yp, ML, Wo, b_o, x, out);
}

// Round 8
// 99.802 us; speedup vs baseline: 4.6843x; 1.0944x over previous
//
#include <hip/hip_runtime.h>

#define BB 4
#define CC 256
#define NN 4096
#define II 128
#define NSPLIT 4
#define KVH (NN / NSPLIT)   // 1024 KV rows per split
#define NT (KVH / 64)       // 16 tiles per split
#define LOG2E 1.4426950408889634f

typedef float f32x4 __attribute__((ext_vector_type(4)));
typedef _Float16 f16x8 __attribute__((ext_vector_type(8)));

static __device__ __forceinline__ unsigned short f2h(float f) {
    _Float16 h = (_Float16)f;
    return __builtin_bit_cast(unsigned short, h);
}
static __device__ __forceinline__ float h2f(unsigned short s) {
    return (float)__builtin_bit_cast(_Float16, s);
}
static __device__ __forceinline__ unsigned int pack2h(float a, float b) {
    return (unsigned int)f2h(a) | ((unsigned int)f2h(b) << 16);
}
static __device__ __forceinline__ unsigned int cvt2h(float a, float b) {
    return __builtin_bit_cast(unsigned int, __builtin_amdgcn_cvt_pkrtz(a, b));
}
#define M3(a, b, c) fmaxf(fmaxf((a), (b)), (c))

// ---------------- MFMA projection: one (mat, batch, 64-n strip) per block ----------------
// mat0->Q (scaled by log2e), mat1->K, mat2->V^T (+ block x==0 converts w_out -> Wo fp16)
__global__ __launch_bounds__(256) void proj_kernel(
    const float* __restrict__ x,
    const float* __restrict__ w_th, const float* __restrict__ b_th,
    const float* __restrict__ w_ph, const float* __restrict__ b_ph,
    const float* __restrict__ w_g,  const float* __restrict__ b_g,
    const float* __restrict__ w_out,
    unsigned short* __restrict__ Qb, unsigned short* __restrict__ Kb,
    unsigned short* __restrict__ Vt, unsigned short* __restrict__ Wo)
{
    __shared__ char lds[24576];
    unsigned short* wl = (unsigned short*)lds;            // [128 i][64 c] fp16, 128B rows, swz
    unsigned short* xl = (unsigned short*)(lds + 16384);  // [64 n][64 c]  fp16, 128B rows, swz

    int tid = threadIdx.x;
    int w = tid >> 6, l = tid & 63, g = l >> 4, cl = l & 15;
    int mat = blockIdx.z, b = blockIdx.y, n0 = blockIdx.x * 64;
    const float* wp = (mat == 0) ? w_th : (mat == 1) ? w_ph : w_g;
    const float* bp = (mat == 0) ? b_th : (mat == 1) ? b_ph : b_g;

    f32x4 acc[2][4];
    #pragma unroll
    for (int it = 0; it < 2; ++it)
        #pragma unroll
        for (int nt = 0; nt < 4; ++nt) acc[it][nt] = (f32x4){0.f, 0.f, 0.f, 0.f};

    const float* xb = x + (size_t)b * CC * NN;
    int c2 = tid >> 3, nch = tid & 7;   // x-staging: c-pair, n-chunk

    for (int c0 = 0; c0 < CC; c0 += 64) {
        __syncthreads();
        #pragma unroll
        for (int r = 0; r < 4; ++r) {
            int idx = r * 256 + tid;
            int row = idx >> 3, ch = idx & 7;
            const float* src = wp + row * CC + c0 + ch * 8;
            float4 a = *(const float4*)src;
            float4 bq = *(const float4*)(src + 4);
            union { unsigned int u[4]; uint4 q; } pk;
            pk.u[0] = pack2h(a.x, a.y);  pk.u[1] = pack2h(a.z, a.w);
            pk.u[2] = pack2h(bq.x, bq.y); pk.u[3] = pack2h(bq.z, bq.w);
            *(uint4*)((char*)wl + row * 128 + ((ch ^ (row & 7)) << 4)) = pk.q;
        }
        {
            const float* xsrc = xb + (size_t)(c0 + c2 * 2) * NN + n0 + nch * 8;
            float4 x00 = *(const float4*)xsrc;
            float4 x01 = *(const float4*)(xsrc + 4);
            float4 x10 = *(const float4*)(xsrc + NN);
            float4 x11 = *(const float4*)(xsrc + NN + 4);
            float lo[8] = {x00.x, x00.y, x00.z, x00.w, x01.x, x01.y, x01.z, x01.w};
            float hi[8] = {x10.x, x10.y, x10.z, x10.w, x11.x, x11.y, x11.z, x11.w};
            #pragma unroll
            for (int t = 0; t < 8; ++t) {
                int n = nch * 8 + t;
                *(unsigned int*)((char*)xl + n * 128 + ((c2 * 4) ^ ((n & 7) << 4))) = pack2h(lo[t], hi[t]);
            }
        }
        __syncthreads();
        #pragma unroll
        for (int kc = 0; kc < 2; ++kc) {
            f16x8 af[2], bf[4];
            #pragma unroll
            for (int it = 0; it < 2; ++it) {
                int row = w * 32 + it * 16 + cl;
                af[it] = *(const f16x8*)((const char*)wl + row * 128 + (((kc * 4 + g) ^ (row & 7)) << 4));
            }
            #pragma unroll
            for (int nt = 0; nt < 4; ++nt) {
                int row = nt * 16 + cl;
                bf[nt] = *(const f16x8*)((const char*)xl + row * 128 + (((kc * 4 + g) ^ (row & 7)) << 4));
            }
            #pragma unroll
            for (int it = 0; it < 2; ++it)
                #pragma unroll
                for (int nt = 0; nt < 4; ++nt)
                    acc[it][nt] = __builtin_amdgcn_mfma_f32_16x16x32_f16(af[it], bf[nt], acc[it][nt], 0, 0, 0);
        }
    }

    float bv[2][4];
    #pragma unroll
    for (int it = 0; it < 2; ++it)
        #pragma unroll
        for (int r = 0; r < 4; ++r) bv[it][r] = bp[w * 32 + it * 16 + 4 * g + r];
    float scale = (mat == 0) ? LOG2E : 1.0f;

    __syncthreads();
    if (mat < 2) {
        unsigned short* pk = (unsigned short*)lds;
        #pragma unroll
        for (int it = 0; it < 2; ++it)
            #pragma unroll
            for (int nt = 0; nt < 4; ++nt)
                #pragma unroll
                for (int r = 0; r < 4; r += 2) {
                    int n = nt * 16 + cl;
                    int i = w * 32 + it * 16 + 4 * g + r;
                    unsigned int v = pack2h((acc[it][nt][r] + bv[it][r]) * scale,
                                            (acc[it][nt][r + 1] + bv[it][r + 1]) * scale);
                    *(unsigned int*)((char*)pk + n * 256 + ((i * 2) ^ ((n & 7) << 4))) = v;
                }
        __syncthreads();
        unsigned short* out = (mat == 0) ? Qb : Kb;
        #pragma unroll
        for (int r = 0; r < 4; ++r) {
            int idx = r * 256 + tid;
            int n = idx >> 4, seg = idx & 15;
            uint4 q = *(const uint4*)((const char*)pk + n * 256 + ((seg << 4) ^ ((n & 7) << 4)));
            *(uint4*)(out + (size_t)(b * NN + n0 + n) * II + seg * 8) = q;
        }
    } else {
        unsigned short* pk = (unsigned short*)lds;
        #pragma unroll
        for (int it = 0; it < 2; ++it)
            #pragma unroll
            for (int nt = 0; nt < 4; ++nt)
                #pragma unroll
                for (int r = 0; r < 4; ++r) {
                    int i = w * 32 + it * 16 + 4 * g + r;
                    int n = nt * 16 + cl;
                    *(unsigned short*)((char*)pk + i * 128 + ((n * 2) ^ ((i & 7) << 4))) =
                        f2h(acc[it][nt][r] + bv[it][r]);
                }
        __syncthreads();
        #pragma unroll
        for (int r = 0; r < 4; ++r) {
            int idx = r * 256 + tid;
            int i = idx >> 3, seg = idx & 7;
            uint4 q = *(const uint4*)((const char*)pk + i * 128 + ((seg << 4) ^ ((i & 7) << 4)));
            *(uint4*)(Vt + (size_t)(b * II + i) * NN + n0 + seg * 8) = q;
        }
        // fold in w_out f32 -> fp16 (one block only)
        if (blockIdx.x == 0) {
            #pragma unroll
            for (int r = 0; r < 16; ++r) {
                int idx = (r * 256 + tid) * 8;
                float4 a = *(const float4*)(w_out + idx);
                float4 b4 = *(const float4*)(w_out + idx + 4);
                union { unsigned int u[4]; uint4 q; } pw;
                pw.u[0] = pack2h(a.x, a.y);   pw.u[1] = pack2h(a.z, a.w);
                pw.u[2] = pack2h(b4.x, b4.y); pw.u[3] = pack2h(b4.z, b4.w);
                *(uint4*)&Wo[idx] = pw.q;
            }
        }
    }
}

// ---------------- flash attention: 32 q/wave, reg P, MFMA ones-row denominator ----------------
__global__ __launch_bounds__(256, 2) void attn_kernel(
    const unsigned short* __restrict__ Qb,   // [B][N][II] fp16 (pre-scaled by log2e)
    const unsigned short* __restrict__ Kb,   // [B][N][II] fp16
    const unsigned short* __restrict__ Vb,   // [B][II][N] fp16
    unsigned short* __restrict__ Yp,         // [NSPLIT][B][N][II] fp16 normalized partial
    float2* __restrict__ ML)                 // [NSPLIT][B][N] {m,l} (base-2 domain)
{
    __shared__ unsigned short Ks[64 * 128];   // [k][c] 256B rows, XOR-swizzled (16 KB)
    __shared__ unsigned short Vs[128 * 64];   // [i][col'(k)] 128B rows, XOR-swizzled (16 KB)

    int tid = threadIdx.x;
    int w = tid >> 6, l = tid & 63, g = l >> 4, cl = l & 15;
    int id = blockIdx.x;
    int comb = (id & 7) * 2 + ((id >> 3) & 1);
    int b = comb >> 2, sp = comb & 3, qt = id >> 4;
    int qr0 = qt * 128;
    int m_base = sp * KVH;

    f16x8 qa0[4], qa1[4];
    {
        const unsigned short* qrow0 = Qb + (size_t)(b * NN + qr0 + w * 32 + cl) * II;
        const unsigned short* qrow1 = qrow0 + 16 * II;
        #pragma unroll
        for (int kc = 0; kc < 4; ++kc) {
            qa0[kc] = *(const f16x8*)(qrow0 + kc * 32 + g * 8);
            qa1[kc] = *(const f16x8*)(qrow1 + kc * 32 + g * 8);
        }
    }
    const f16x8 onesv = {(_Float16)1.f, (_Float16)1.f, (_Float16)1.f, (_Float16)1.f,
                         (_Float16)1.f, (_Float16)1.f, (_Float16)1.f, (_Float16)1.f};

    f32x4 yacc0[8], yacc1[8], lacc0, lacc1;
    #pragma unroll
    for (int it = 0; it < 8; ++it) {
        yacc0[it] = (f32x4){0.f, 0.f, 0.f, 0.f};
        yacc1[it] = (f32x4){0.f, 0.f, 0.f, 0.f};
    }
    lacc0 = (f32x4){0.f, 0.f, 0.f, 0.f};
    lacc1 = (f32x4){0.f, 0.f, 0.f, 0.f};
    float mrun0 = -1e30f, mrun1 = -1e30f;

    const unsigned short* kb = Kb + (size_t)(b * NN + m_base) * II;
    const unsigned short* vb = Vb + (size_t)b * II * NN + m_base;
    int krow = tid >> 4, kch = tid & 15;
    int vrow = tid >> 3, vch = tid & 7;
    int kswz = (kch ^ (krow & 7)) << 4;
    int vsw = (vrow & 7) << 4;
    int vc0 = ((vch >> 2) * 32 + (vch & 1) * 16 + ((vch >> 1) & 1) * 4) * 2;

    uint4 k0, k1, k2, k3, v0, v1, v2, v3;   // named regs (no PromoteAlloca)
    k0 = *(const uint4*)(kb + (size_t)(krow) * II + kch * 8);
    k1 = *(const uint4*)(kb + (size_t)(16 + krow) * II + kch * 8);
    k2 = *(const uint4*)(kb + (size_t)(32 + krow) * II + kch * 8);
    k3 = *(const uint4*)(kb + (size_t)(48 + krow) * II + kch * 8);
    v0 = *(const uint4*)(vb + (size_t)(vrow) * NN + vch * 8);
    v1 = *(const uint4*)(vb + (size_t)(32 + vrow) * NN + vch * 8);
    v2 = *(const uint4*)(vb + (size_t)(64 + vrow) * NN + vch * 8);
    v3 = *(const uint4*)(vb + (size_t)(96 + vrow) * NN + vch * 8);

    for (int t = 0; t < NT; ++t) {
        __syncthreads();
        *(uint4*)((char*)Ks + (krow) * 256 + kswz) = k0;
        *(uint4*)((char*)Ks + (16 + krow) * 256 + kswz) = k1;
        *(uint4*)((char*)Ks + (32 + krow) * 256 + kswz) = k2;
        *(uint4*)((char*)Ks + (48 + krow) * 256 + kswz) = k3;
        {
            uint2 lo, hi;
            lo.x = v0.x; lo.y = v0.y; hi.x = v0.z; hi.y = v0.w;
            *(uint2*)((char*)Vs + (vrow) * 128 + (vc0 ^ vsw)) = lo;
            *(uint2*)((char*)Vs + (vrow) * 128 + ((vc0 + 16) ^ vsw)) = hi;
            lo.x = v1.x; lo.y = v1.y; hi.x = v1.z; hi.y = v1.w;
            *(uint2*)((char*)Vs + (32 + vrow) * 128 + (vc0 ^ vsw)) = lo;
            *(uint2*)((char*)Vs + (32 + vrow) * 128 + ((vc0 + 16) ^ vsw)) = hi;
            lo.x = v2.x; lo.y = v2.y; hi.x = v2.z; hi.y = v2.w;
            *(uint2*)((char*)Vs + (64 + vrow) * 128 + (vc0 ^ vsw)) = lo;
            *(uint2*)((char*)Vs + (64 + vrow) * 128 + ((vc0 + 16) ^ vsw)) = hi;
            lo.x = v3.x; lo.y = v3.y; hi.x = v3.z; hi.y = v3.w;
            *(uint2*)((char*)Vs + (96 + vrow) * 128 + (vc0 ^ vsw)) = lo;
            *(uint2*)((char*)Vs + (96 + vrow) * 128 + ((vc0 + 16) ^ vsw)) = hi;
        }
        __syncthreads();
        if (t + 1 < NT) {
            const unsigned short* kp = kb + (size_t)(t + 1) * 64 * II;
            k0 = *(const uint4*)(kp + (size_t)(krow) * II + kch * 8);
            k1 = *(const uint4*)(kp + (size_t)(16 + krow) * II + kch * 8);
            k2 = *(const uint4*)(kp + (size_t)(32 + krow) * II + kch * 8);
            k3 = *(const uint4*)(kp + (size_t)(48 + krow) * II + kch * 8);
        }

        // ---- S^T = K Q^T for both q-groups, each K fragment read ONCE ----
        f32x4 s0[4], s1[4];
        #pragma unroll
        for (int mt = 0; mt < 4; ++mt) {
            s0[mt] = (f32x4){0.f, 0.f, 0.f, 0.f};
            s1[mt] = (f32x4){0.f, 0.f, 0.f, 0.f};
        }
        __builtin_amdgcn_s_setprio(1);
        #pragma unroll
        for (int mt = 0; mt < 4; ++mt) {
            int row = mt * 16 + cl;
            #pragma unroll
            for (int kc = 0; kc < 4; ++kc) {
                f16x8 kf = *(const f16x8*)((const char*)Ks + row * 256 + (((kc * 4 + g) ^ (row & 7)) << 4));
                s0[mt] = __builtin_amdgcn_mfma_f32_16x16x32_f16(kf, qa0[kc], s0[mt], 0, 0, 0);
                s1[mt] = __builtin_amdgcn_mfma_f32_16x16x32_f16(kf, qa1[kc], s1[mt], 0, 0, 0);
            }
        }
        __builtin_amdgcn_s_setprio(0);
        if (t + 1 < NT) {
            const unsigned short* vp = vb + (size_t)(t + 1) * 64;
            v0 = *(const uint4*)(vp + (size_t)(vrow) * NN + vch * 8);
            v1 = *(const uint4*)(vp + (size_t)(32 + vrow) * NN + vch * 8);
            v2 = *(const uint4*)(vp + (size_t)(64 + vrow) * NN + vch * 8);
            v3 = *(const uint4*)(vp + (size_t)(96 + vrow) * NN + vch * 8);
        }

        // ---- softmax q-group 0 (in-lane, base-2, defer-rescale, packed cvt) ----
        union { unsigned int u[4]; f16x8 v; } pb00, pb01, pb10, pb11;
        {
            float t0 = M3(s0[0][0], s0[0][1], s0[0][2]);
            float t1 = M3(s0[0][3], s0[1][0], s0[1][1]);
            float t2 = M3(s0[1][2], s0[1][3], s0[2][0]);
            float t3 = M3(s0[2][1], s0[2][2], s0[2][3]);
            float t4 = M3(s0[3][0], s0[3][1], s0[3][2]);
            float tmax = fmaxf(M3(t0, t1, t2), M3(t3, t4, s0[3][3]));
            tmax = fmaxf(tmax, __shfl_xor(tmax, 16));
            tmax = fmaxf(tmax, __shfl_xor(tmax, 32));
            if (!__all(tmax <= mrun0 + 8.0f)) {
                float mnew = fmaxf(mrun0, tmax);
                float corr = exp2f(mrun0 - mnew);
                mrun0 = mnew;
                #pragma unroll
                for (int it = 0; it < 8; ++it)
                    #pragma unroll
                    for (int r = 0; r < 4; ++r) yacc0[it][r] *= corr;
                #pragma unroll
                for (int r = 0; r < 4; ++r) lacc0[r] *= corr;
            }
            #pragma unroll
            for (int mt = 0; mt < 4; ++mt) {
                unsigned int ua = cvt2h(exp2f(s0[mt][0] - mrun0), exp2f(s0[mt][1] - mrun0));
                unsigned int ub = cvt2h(exp2f(s0[mt][2] - mrun0), exp2f(s0[mt][3] - mrun0));
                if (mt < 2) { pb00.u[mt * 2] = ua; pb00.u[mt * 2 + 1] = ub; }
                else        { pb01.u[(mt - 2) * 2] = ua; pb01.u[(mt - 2) * 2 + 1] = ub; }
            }
        }
        // ---- softmax q-group 1 ----
        {
            float t0 = M3(s1[0][0], s1[0][1], s1[0][2]);
            float t1 = M3(s1[0][3], s1[1][0], s1[1][1]);
            float t2 = M3(s1[1][2], s1[1][3], s1[2][0]);
            float t3 = M3(s1[2][1], s1[2][2], s1[2][3]);
            float t4 = M3(s1[3][0], s1[3][1], s1[3][2]);
            float tmax = fmaxf(M3(t0, t1, t2), M3(t3, t4, s1[3][3]));
            tmax = fmaxf(tmax, __shfl_xor(tmax, 16));
            tmax = fmaxf(tmax, __shfl_xor(tmax, 32));
            if (!__all(tmax <= mrun1 + 8.0f)) {
                float mnew = fmaxf(mrun1, tmax);
                float corr = exp2f(mrun1 - mnew);
                mrun1 = mnew;
                #pragma unroll
                for (int it = 0; it < 8; ++it)
                    #pragma unroll
                    for (int r = 0; r < 4; ++r) yacc1[it][r] *= corr;
                #pragma unroll
                for (int r = 0; r < 4; ++r) lacc1[r] *= corr;
            }
            #pragma unroll
            for (int mt = 0; mt < 4; ++mt) {
                unsigned int ua = cvt2h(exp2f(s1[mt][0] - mrun1), exp2f(s1[mt][1] - mrun1));
                unsigned int ub = cvt2h(exp2f(s1[mt][2] - mrun1), exp2f(s1[mt][3] - mrun1));
                if (mt < 2) { pb10.u[mt * 2] = ua; pb10.u[mt * 2 + 1] = ub; }
                else        { pb11.u[(mt - 2) * 2] = ua; pb11.u[(mt - 2) * 2 + 1] = ub; }
            }
        }

        // ---- Y^T += V^T P^T (V fragment read once, feeds both groups); l via ones-row ----
        __builtin_amdgcn_s_setprio(1);
        lacc0 = __builtin_amdgcn_mfma_f32_16x16x32_f16(onesv, pb00.v, lacc0, 0, 0, 0);
        lacc0 = __builtin_amdgcn_mfma_f32_16x16x32_f16(onesv, pb01.v, lacc0, 0, 0, 0);
        lacc1 = __builtin_amdgcn_mfma_f32_16x16x32_f16(onesv, pb10.v, lacc1, 0, 0, 0);
        lacc1 = __builtin_amdgcn_mfma_f32_16x16x32_f16(onesv, pb11.v, lacc1, 0, 0, 0);
        #pragma unroll
        for (int it = 0; it < 8; ++it) {
            int row = it * 16 + cl;
            f16x8 vf0 = *(const f16x8*)((const char*)Vs + row * 128 + ((g ^ (row & 7)) << 4));
            f16x8 vf1 = *(const f16x8*)((const char*)Vs + row * 128 + (((4 + g) ^ (row & 7)) << 4));
            yacc0[it] = __builtin_amdgcn_mfma_f32_16x16x32_f16(vf0, pb00.v, yacc0[it], 0, 0, 0);
            yacc0[it] = __builtin_amdgcn_mfma_f32_16x16x32_f16(vf1, pb01.v, yacc0[it], 0, 0, 0);
            yacc1[it] = __builtin_amdgcn_mfma_f32_16x16x32_f16(vf0, pb10.v, yacc1[it], 0, 0, 0);
            yacc1[it] = __builtin_amdgcn_mfma_f32_16x16x32_f16(vf1, pb11.v, yacc1[it], 0, 0, 0);
        }
        __builtin_amdgcn_s_setprio(0);
    }

    __syncthreads();   // all waves done reading Ks/Vs

    // ---- normalize, park per wave in Ks, dense stores (per q-group) ----
    unsigned short* ys = Ks + w * 2048;   // [16 q][128 i], 256B rows, swz
    size_t rowbase0 = (size_t)((sp * BB + b) * NN + qr0 + w * 32);
    int prow = l >> 2;
    {
        float rl = 1.0f / lacc0[0];
        #pragma unroll
        for (int it = 0; it < 8; ++it)
            #pragma unroll
            for (int r = 0; r < 4; r += 2) {
                int i = it * 16 + 4 * g + r;
                *(unsigned int*)((char*)ys + cl * 256 + ((i * 2) ^ ((cl & 7) << 4))) =
                    pack2h(yacc0[it][r] * rl, yacc0[it][r + 1] * rl);
            }
        #pragma unroll
        for (int c = 0; c < 4; ++c) {
            int seg = c * 4 + (l & 3);
            uint4 q = *(const uint4*)((const char*)ys + prow * 256 + ((seg << 4) ^ ((prow & 7) << 4)));
            *(uint4*)(Yp + (rowbase0 + prow) * II + seg * 8) = q;
        }
    }
    {
        float rl = 1.0f / lacc1[0];
        #pragma unroll
        for (int it = 0; it < 8; ++it)
            #pragma unroll
            for (int r = 0; r < 4; r += 2) {
                int i = it * 16 + 4 * g + r;
                *(unsigned int*)((char*)ys + cl * 256 + ((i * 2) ^ ((cl & 7) << 4))) =
                    pack2h(yacc1[it][r] * rl, yacc1[it][r + 1] * rl);
            }
        #pragma unroll
        for (int c = 0; c < 4; ++c) {
            int seg = c * 4 + (l & 3);
            uint4 q = *(const uint4*)((const char*)ys + prow * 256 + ((seg << 4) ^ ((prow & 7) << 4)));
            *(uint4*)(Yp + (rowbase0 + 16 + prow) * II + seg * 8) = q;
        }
    }
    if (l < 16) {
        float2 v; v.x = mrun0; v.y = lacc0[0];
        ML[rowbase0 + l] = v;
    } else if (l < 32) {
        float2 v; v.x = mrun1; v.y = lacc1[0];
        ML[rowbase0 + 16 + (l - 16)] = v;
    }
}

// ---------------- combine partials + output conv + bias + residual ----------------
__global__ __launch_bounds__(256) void combine_kernel(
    const unsigned short* __restrict__ Yp, const float2* __restrict__ ML,
    const unsigned short* __restrict__ Wo, const float* __restrict__ b_out,
    const float* __restrict__ x, float* __restrict__ out)
{
    __shared__ unsigned short Ys[4][16 * 128];   // per-wave park, swizzled 256B rows

    int tid = threadIdx.x;
    int w = tid >> 6, l = tid & 63, g = l >> 4, cl = l & 15;
    int qt = blockIdx.x, b = blockIdx.y;
    int qr0 = qt * 64;
    int n = qr0 + w * 16 + cl;

    float ms[NSPLIT], ls[NSPLIT], wgt[NSPLIT];
    float M = -1e30f;
    #pragma unroll
    for (int s = 0; s < NSPLIT; ++s) {
        float2 ml = ML[(size_t)(s * BB + b) * NN + n];
        ms[s] = ml.x; ls[s] = ml.y;
        M = fmaxf(M, ml.x);
    }
    float wsum = 0.f;
    #pragma unroll
    for (int s = 0; s < NSPLIT; ++s) { wgt[s] = exp2f(ms[s] - M) * ls[s]; wsum += wgt[s]; }
    float rd = 1.0f / wsum;
    #pragma unroll
    for (int s = 0; s < NSPLIT; ++s) wgt[s] *= rd;

    unsigned short* ys = Ys[w];
    #pragma unroll
    for (int j = 0; j < 4; ++j) {
        float acc[8];
        #pragma unroll
        for (int e = 0; e < 8; ++e) acc[e] = 0.f;
        #pragma unroll
        for (int s = 0; s < NSPLIT; ++s) {
            union { unsigned short s16[8]; uint4 q; } a;
            a.q = *(const uint4*)(Yp + ((size_t)(s * BB + b) * NN + n) * II + g * 32 + j * 8);
            #pragma unroll
            for (int e = 0; e < 8; ++e) acc[e] += wgt[s] * h2f(a.s16[e]);
        }
        union { unsigned int u[4]; uint4 q; } o;
        #pragma unroll
        for (int e = 0; e < 4; ++e) o.u[e] = pack2h(acc[e * 2], acc[e * 2 + 1]);
        *(uint4*)((char*)ys + cl * 256 + (((g * 4 + j) ^ (cl & 7)) << 4)) = o.q;
    }
    // same-wave write->read; no barrier needed

    f32x4 zero4 = {0.f, 0.f, 0.f, 0.f};
    f16x8 yf[4];
    #pragma unroll
    for (int kc = 0; kc < 4; ++kc)
        yf[kc] = *(const f16x8*)((const char*)ys + cl * 256 + (((kc * 4 + g) ^ (cl & 7)) << 4));
    for (int ct = 0; ct < 16; ++ct) {
        f32x4 oa = zero4;
        #pragma unroll
        for (int kc = 0; kc < 4; ++kc) {
            f16x8 wf = *(const f16x8*)(Wo + (ct * 16 + cl) * II + kc * 32 + g * 8);
            oa = __builtin_amdgcn_mfma_f32_16x16x32_f16(wf, yf[kc], oa, 0, 0, 0);
        }
        #pragma unroll
        for (int r = 0; r < 4; ++r) {
            int c = ct * 16 + 4 * g + r;
            size_t off = (size_t)(b * CC + c) * NN + n;
            out[off] = oa[r] + b_out[c] + x[off];
        }
    }
}

extern "C" void kernel_launch(void* const* d_in, const int* in_sizes, int n_in,
                              void* d_out, int out_size, void* d_ws, size_t ws_size,
                              hipStream_t stream) {
    const float* x     = (const float*)d_in[0];
    const float* w_g   = (const float*)d_in[1];
    const float* b_g   = (const float*)d_in[2];
    const float* w_th  = (const float*)d_in[3];
    const float* b_th  = (const float*)d_in[4];
    const float* w_ph  = (const float*)d_in[5];
    const float* b_ph  = (const float*)d_in[6];
    const float* w_out = (const float*)d_in[7];
    const float* b_o   = (const float*)d_in[8];
    float* out = (float*)d_out;

    const size_t SZ = (size_t)BB * NN * II;
    unsigned short* Qb = (unsigned short*)d_ws;
    unsigned short* Kb = Qb + SZ;
    unsigned short* Vt = Kb + SZ;
    unsigned short* Wo = Vt + SZ;
    unsigned short* Yp = Wo + (size_t)CC * II;                 // NSPLIT * SZ fp16
    float2*         ML = (float2*)(Yp + (size_t)NSPLIT * SZ);  // NSPLIT*B*N float2

    proj_kernel<<<dim3(NN / 64, BB, 3), dim3(256), 0, stream>>>(
        x, w_th, b_th, w_ph, b_ph, w_g, b_g, w_out, Qb, Kb, Vt, Wo);
    attn_kernel<<<dim3(NSPLIT * BB * (NN / 128)), dim3(256), 0, stream>>>(
        Qb, Kb, Vt, Yp, ML);
    combine_kernel<<<dim3(NN / 64, BB), dim3(256), 0, stream>>>(Yp, ML, Wo, b_o, x, out);
}